// Round 9
// baseline (166.142 us; speedup 1.0000x reference)
//
#include <hip/hip_runtime.h>
#include <stdint.h>
#include <math.h>

#define HFM 64
#define WFM 128
#define CFM 128
#define BN 2
#define HWFM (HFM*WFM)          // 8192
#define NPIX (BN*HWFM)          // 16384
#define KQ 6000
#define KQP 6144                // padded to 48*128 (rows 6000..6143 zero)
#define NNEG 60
#define NE (NPIX*NNEG)          // 983040
#define EHALF_U 491520u
#define MSHIFT 15.0f
#define LOG2E 1.4426950408889634f

typedef _Float16 f16_8 __attribute__((ext_vector_type(8)));
typedef _Float16 f16_2 __attribute__((ext_vector_type(2)));
typedef float f32_4 __attribute__((ext_vector_type(4)));

// ---------------- JAX threefry2x32 (bit-exact) ----------------
__host__ __device__ __forceinline__ void threefry2x32(uint32_t k0, uint32_t k1,
                                                      uint32_t x0, uint32_t x1,
                                                      uint32_t* o0, uint32_t* o1) {
  uint32_t ks2 = k0 ^ k1 ^ 0x1BD11BDAu;
  x0 += k0; x1 += k1;
#define TFR(r) { x0 += x1; x1 = (x1 << (r)) | (x1 >> (32 - (r))); x1 ^= x0; }
  TFR(13) TFR(15) TFR(26) TFR(6)
  x0 += k1;  x1 += ks2 + 1u;
  TFR(17) TFR(29) TFR(16) TFR(24)
  x0 += ks2; x1 += k0 + 2u;
  TFR(13) TFR(15) TFR(26) TFR(6)
  x0 += k0;  x1 += k1 + 3u;
  TFR(17) TFR(29) TFR(16) TFR(24)
  x0 += k1;  x1 += ks2 + 4u;
  TFR(13) TFR(15) TFR(26) TFR(6)
  x0 += ks2; x1 += k0 + 5u;
#undef TFR
  *o0 = x0; *o1 = x1;
}

// grid_sample coordinate helper (reference op order)
__device__ __forceinline__ void gs_coord(float t, float halfdim, float maxc,
                                         int* i0, int* i1, float* w) {
  float g = 2.0f * t - 1.0f;
  float x = (g + 1.0f) * halfdim - 0.5f;
  x = fminf(fmaxf(x, 0.0f), maxc);
  float f = floorf(x);
  *i0 = (int)f;
  *w = x - f;
  *i1 = (int)fminf(f + 1.0f, maxc);
}

// ref [b,c,hw] -> refTf f16 [b,hw,c];  tgt [b,c,hw] -> tgtTf f16 [b,hw,c]
__global__ void k_transpose(const float* __restrict__ ref, const float* __restrict__ tgt,
                            _Float16* __restrict__ refTf, _Float16* __restrict__ tgtTf) {
  __shared__ float tile[32][33];
  int z = blockIdx.z;
  int arr = z >> 1, b = z & 1;
  const float* src = (arr == 0 ? ref : tgt) + (size_t)b * CFM * HWFM;
  _Float16* dst = (arr == 0 ? refTf : tgtTf) + (size_t)b * HWFM * CFM;
  int x0 = blockIdx.x * 32;   // hw
  int y0 = blockIdx.y * 32;   // c
  int tx = threadIdx.x, ty = threadIdx.y;
#pragma unroll
  for (int i = 0; i < 32; i += 8)
    tile[ty + i][tx] = src[(size_t)(y0 + ty + i) * HWFM + x0 + tx];
  __syncthreads();
#pragma unroll
  for (int i = 0; i < 32; i += 8)
    dst[(size_t)(x0 + ty + i) * CFM + (y0 + tx)] = (_Float16)tile[tx][ty + i];
}

// transpose queue [128][6000] fp32 -> [6144][128] f16 (rows 6000..6143 zero)
__global__ void k_qtrans(const float* __restrict__ queue, _Float16* __restrict__ queueTf) {
  __shared__ float tile[32][33];
  int n0 = blockIdx.x * 32;   // queue col
  int c0 = blockIdx.y * 32;   // channel
  int tx = threadIdx.x, ty = threadIdx.y;
#pragma unroll
  for (int i = 0; i < 32; i += 8) {
    int n = n0 + tx;
    tile[ty + i][tx] = (n < KQ) ? queue[(size_t)(c0 + ty + i) * KQ + n] : 0.0f;
  }
  __syncthreads();
#pragma unroll
  for (int i = 0; i < 32; i += 8)
    queueTf[(size_t)(n0 + ty + i) * CFM + (c0 + tx)] = (_Float16)tile[tx][ty + i];
}

// queue column exp-prep: qeb[n] = (qInv*log2e/T, -15*log2e); pad: (0, -1000)
__global__ void k_qprep(const float* __restrict__ queue, float2* __restrict__ qeb) {
  int k = blockIdx.x * 256 + threadIdx.x;
  if (k >= KQP) return;
  if (k >= KQ) { qeb[k] = make_float2(0.0f, -1000.0f); return; }
  float ss = 0.0f;
  for (int c = 0; c < CFM; c++) { float v = queue[c * KQ + k]; ss += v * v; }
  float qi = 1.0f / fmaxf(sqrtf(ss), 1e-12f);
  qeb[k] = make_float2(qi * (LOG2E / 0.07f), -MSHIFT * LOG2E);
}

// per-(batch,x) column stats over rows y=0,1 of tgtTf
__global__ __launch_bounds__(64) void k_colstats(const _Float16* __restrict__ tgtTf,
                                                 float* __restrict__ stats) {
  int b = blockIdx.x >> 7, x = blockIdx.x & 127;
  int xp = min(x + 1, 127);
  int lane = threadIdx.x;
  int c2 = lane * 2;
  int base = b * HWFM;
  f16_2 c0  = *(const f16_2*)(tgtTf + (size_t)(base + x) * CFM + c2);
  f16_2 c1  = *(const f16_2*)(tgtTf + (size_t)(base + WFM + x) * CFM + c2);
  f16_2 c0p = *(const f16_2*)(tgtTf + (size_t)(base + xp) * CFM + c2);
  f16_2 c1p = *(const f16_2*)(tgtTf + (size_t)(base + WFM + xp) * CFM + c2);
  float a0 = (float)c0[0], a1 = (float)c0[1];
  float b0 = (float)c1[0], b1 = (float)c1[1];
  float p0 = (float)c0p[0], p1 = (float)c0p[1];
  float q0 = (float)c1p[0], q1 = (float)c1p[1];
  float s[7];
  s[0] = a0 * a0 + a1 * a1;
  s[1] = a0 * b0 + a1 * b1;
  s[2] = b0 * b0 + b1 * b1;
  s[3] = a0 * p0 + a1 * p1;
  s[4] = a0 * q0 + a1 * q1;
  s[5] = b0 * p0 + b1 * p1;
  s[6] = b0 * q0 + b1 * q1;
#pragma unroll
  for (int o = 32; o; o >>= 1)
#pragma unroll
    for (int k = 0; k < 7; k++) s[k] += __shfl_xor(s[k], o, 64);
  if (lane == 0) {
    float* st = stats + (size_t)(b * 128 + x) * 8;
#pragma unroll
    for (int k = 0; k < 7; k++) st[k] = s[k];
    st[7] = 0.0f;
  }
}

// per pixel (wave-per-pixel): mask; if unmasked: fused query normalize,
// positive dot, l_pos, xr, S store.
__global__ __launch_bounds__(256) void k_prelude(
    const float* __restrict__ target_l, const float* __restrict__ target_r,
    const _Float16* __restrict__ refTf, const _Float16* __restrict__ tgtTf,
    _Float16* __restrict__ QTf,
    float* __restrict__ S, float* __restrict__ logit0,
    float* __restrict__ maskArr, float* __restrict__ xr) {
  int tid = threadIdx.x;
  int wave = tid >> 6, lane = tid & 63;
  int p = blockIdx.x * 4 + wave;
  int b = p >> 13;
  int rem = p & (HWFM - 1);
  int i = rem >> 7, j = rem & 127;
  const float stepx = 1.0f / 127.0f, stepy = 1.0f / 63.0f;
  float xb = (j == 127) ? 1.0f : j * stepx;
  float yb = (i == 63) ? 1.0f : i * stepy;
  const float* tl = target_l + (size_t)b * 256 * 512;
  const float* tr = target_r + (size_t)b * 256 * 512;

  int c2 = lane * 2;
  f16_2 q2 = *(const f16_2*)(refTf + (size_t)p * CFM + c2);

  float dl = tl[(4 * i) * 512 + 4 * j] * 0.25f;

  int y0i, y1i; float wy;
  gs_coord(yb, 32.0f, 63.0f, &y0i, &y1i, &wy);
  float t = xb - dl * (1.0f / 128.0f);
  int x0i, x1i; float wx;
  gs_coord(t, 64.0f, 127.0f, &x0i, &x1i, &wx);

  int bo = b * HWFM;
  f16_2 a2 = *(const f16_2*)(tgtTf + (size_t)(bo + y0i * WFM + x0i) * CFM + c2);
  f16_2 b2 = *(const f16_2*)(tgtTf + (size_t)(bo + y0i * WFM + x1i) * CFM + c2);
  f16_2 cc2 = *(const f16_2*)(tgtTf + (size_t)(bo + y1i * WFM + x0i) * CFM + c2);
  f16_2 d2 = *(const f16_2*)(tgtTf + (size_t)(bo + y1i * WFM + x1i) * CFM + c2);

  auto innerv = [&](int y, int x) -> float {
    float xbx = (x == 127) ? 1.0f : x * stepx;
    float drv = tr[(4 * y) * 512 + 4 * x] * 0.25f;
    float ti = xbx + drv * (1.0f / 128.0f);
    float g = 2.0f * ti - 1.0f;
    float ix2 = fminf(fmaxf((g + 1.0f) * 64.0f - 0.5f, 0.0f), 127.0f);
    float x0f = floorf(ix2);
    float wxp = ix2 - x0f;
    float x1f = fminf(x0f + 1.0f, 127.0f);
    return x0f * (1.0f - wxp) + x1f * wxp;
  };
  float v00 = innerv(y0i, x0i), v01 = innerv(y0i, x1i);
  float v10 = innerv(y1i, x0i), v11 = innerv(y1i, x1i);
  float l2r2l = v00 * (1.0f - wx) * (1.0f - wy) + v01 * wx * (1.0f - wy)
              + v10 * (1.0f - wx) * wy + v11 * wx * wy;
  bool masko = fabsf((float)j - l2r2l) < 3.0f;
  bool mk = masko && (dl > 0.0f) && (t >= 0.0f);
  if (lane == 0) maskArr[p] = mk ? 1.0f : 0.0f;
  if (!mk) return;

  float w00 = (1.0f - wx) * (1.0f - wy), w01 = wx * (1.0f - wy);
  float w10 = (1.0f - wx) * wy,          w11 = wx * wy;
  float q0 = (float)q2[0], q1 = (float)q2[1];
  float v0 = w00 * (float)a2[0] + w01 * (float)b2[0] + w10 * (float)cc2[0] + w11 * (float)d2[0];
  float v1 = w00 * (float)a2[1] + w01 * (float)b2[1] + w10 * (float)cc2[1] + w11 * (float)d2[1];

  float s0 = q0 * q0 + q1 * q1;
  float s1 = q0 * v0 + q1 * v1;
  float s2 = v0 * v0 + v1 * v1;
#pragma unroll
  for (int o = 32; o; o >>= 1) {
    s0 += __shfl_xor(s0, o, 64);
    s1 += __shfl_xor(s1, o, 64);
    s2 += __shfl_xor(s2, o, 64);
  }
  float inv = 1.0f / fmaxf(sqrtf(s0), 1e-12f);
  f16_2 qw; qw[0] = (_Float16)(q0 * inv); qw[1] = (_Float16)(q1 * inv);
  *(f16_2*)(QTf + (size_t)p * CFM + c2) = qw;
  if (lane == 0) {
    float lpos = (s1 * inv) / fmaxf(sqrtf(s2), 1e-12f);
    float lg0 = lpos / 0.07f;
    logit0[p] = lg0;
    xr[p] = t * 128.0f;
    S[p] = expf(lg0 - MSHIFT);
  }
}

// single-block ballot + prefix-scan compaction (ascending pixel order)
__global__ __launch_bounds__(1024) void k_compact(const float* __restrict__ maskArr,
                                                  int* __restrict__ count,
                                                  int* __restrict__ list) {
  int tid = threadIdx.x;
  int lane = tid & 63, wave = tid >> 6;
  int base_p = tid * 16;
  const float4* m4 = (const float4*)(maskArr + base_p);
  float4 v[4];
#pragma unroll
  for (int k = 0; k < 4; k++) v[k] = m4[k];
  unsigned int bits = 0;
#pragma unroll
  for (int k = 0; k < 4; k++) {
    if (v[k].x > 0.0f) bits |= 1u << (4 * k + 0);
    if (v[k].y > 0.0f) bits |= 1u << (4 * k + 1);
    if (v[k].z > 0.0f) bits |= 1u << (4 * k + 2);
    if (v[k].w > 0.0f) bits |= 1u << (4 * k + 3);
  }
  int m = __popc(bits);
  int scan = m;
#pragma unroll
  for (int off = 1; off < 64; off <<= 1) {
    int n = __shfl_up(scan, off, 64);
    if (lane >= off) scan += n;
  }
  __shared__ int wsum[16];
  if (lane == 63) wsum[wave] = scan;
  __syncthreads();
  int wbase = 0;
  for (int w = 0; w < wave; w++) wbase += wsum[w];
  int idx = wbase + scan - m;
#pragma unroll
  for (int k = 0; k < 16; k++) {
    if (bits & (1u << k)) list[idx++] = base_p + k;
  }
  if (tid == 1023) *count = idx;
}

// -------- D-GEMM: D[slot][x] = dot(C_y[x], q_slot), y=0 cols 0..127, y=1 128..255
__global__ __launch_bounds__(256) void k_dgemm(
    const _Float16* __restrict__ QTf, const _Float16* __restrict__ tgtTf,
    float* __restrict__ D,
    const int* __restrict__ count, const int* __restrict__ list) {
  int tid = threadIdx.x;
  int cnt = *count;
  int pblk = blockIdx.x * 64;
  if (pblk >= cnt) return;
  int wave = tid >> 6, lane = tid & 63;
  int quad = lane >> 4, l16 = lane & 15;
  int wm = wave >> 1, wn = wave & 1;
  int p0 = pblk + wm * 32;

  __shared__ int pb[64];
  if (tid < 64) pb[tid] = list[min(pblk + tid, cnt - 1)] >> 13;
  __syncthreads();

  int prow[2];
#pragma unroll
  for (int mt = 0; mt < 2; mt++)
    prow[mt] = list[min(p0 + mt * 16 + l16, cnt - 1)];

  f16_8 Af[2][4];
#pragma unroll
  for (int mt = 0; mt < 2; mt++) {
    const _Float16* arow = QTf + (size_t)prow[mt] * CFM + quad * 8;
#pragma unroll
    for (int ks = 0; ks < 4; ks++)
      Af[mt][ks] = *(const f16_8*)(arow + ks * 32);
  }

#pragma unroll
  for (int ic = 0; ic < 4; ic++) {
    int colbase = ic * 128;
    int rowbase = (ic < 2) ? ic * 128 : (HWFM + (ic - 2) * 128);
    f16_8 Bf[4][4];
    const _Float16* brow = tgtTf + (size_t)(rowbase + wn * 64 + l16) * CFM + quad * 8;
#pragma unroll
    for (int nt = 0; nt < 4; nt++)
#pragma unroll
      for (int ks = 0; ks < 4; ks++)
        Bf[nt][ks] = *(const f16_8*)(brow + (size_t)nt * 16 * CFM + ks * 32);

    f32_4 acc[2][4];
#pragma unroll
    for (int mt = 0; mt < 2; mt++)
#pragma unroll
      for (int nt = 0; nt < 4; nt++)
        acc[mt][nt] = (f32_4){0.0f, 0.0f, 0.0f, 0.0f};
#pragma unroll
    for (int ks = 0; ks < 4; ks++)
#pragma unroll
      for (int mt = 0; mt < 2; mt++)
#pragma unroll
        for (int nt = 0; nt < 4; nt++)
          acc[mt][nt] = __builtin_amdgcn_mfma_f32_16x16x32_f16(Af[mt][ks], Bf[nt][ks], acc[mt][nt], 0, 0, 0);

#pragma unroll
    for (int mt = 0; mt < 2; mt++)
#pragma unroll
      for (int nt = 0; nt < 4; nt++)
#pragma unroll
        for (int r = 0; r < 4; r++) {
          int rowloc = wm * 32 + mt * 16 + quad * 4 + r;
          int col = colbase + wn * 64 + nt * 16 + l16;
          if ((col >> 8) == pb[rowloc])
            D[(size_t)(pblk + rowloc) * 256 + (col & 255)] = acc[mt][nt][r];
        }
  }
}

// -------- negatives: wave-per-pixel, scalar via D + stats decomposition ----
__global__ __launch_bounds__(256) void k_negatives_lite(
    const float* __restrict__ D, const float* __restrict__ stats,
    const float* __restrict__ xr, float* __restrict__ S,
    const int* __restrict__ count, const int* __restrict__ list,
    uint32_t k1a, uint32_t k1b, uint32_t k2a, uint32_t k2b) {
  int tid = threadIdx.x;
  int wave = tid >> 6, lane = tid & 63;
  int cnt = *count;
  int slot = blockIdx.x * 4 + wave;
  if (slot >= cnt) return;
  int p = list[slot];
  int b = p >> 13;
  float esum = 0.0f;
  if (lane < NNEG) {
    uint32_t e = (uint32_t)(p * NNEG + lane);
    uint32_t h0, h1;
    threefry2x32(k1a, k1b, e, e + (uint32_t)NE, &h0, &h1);
    uint32_t off = ((h0 % 24u) * 16u + (h1 % 24u)) % 24u;
    float mag = (float)(1u + off);
    uint32_t ub;
    {
      uint32_t a, bm;
      if (e < EHALF_U) { threefry2x32(k2a, k2b, e, e + EHALF_U, &a, &bm); ub = a; }
      else             { threefry2x32(k2a, k2b, e - EHALF_U, e, &a, &bm); ub = bm; }
    }
    float u = __uint_as_float((ub >> 9) | 0x3F800000u) - 1.0f;
    float sg = (u > 0.5f) ? 1.0f : ((u < 0.5f) ? -1.0f : 0.0f);

    float v = xr[p] + mag * sg;
    float r = fmodf(v, 128.0f);
    if (r < 0.0f) r += 128.0f;
    float fx = r * (1.0f / 128.0f);
    float fy = fx * (1.0f / 64.0f);
    int x0i, x1i, y0i, y1i; float wx, wy;
    gs_coord(fx, 64.0f, 127.0f, &x0i, &x1i, &wx);
    gs_coord(fy, 32.0f, 63.0f, &y0i, &y1i, &wy);

    const float* Dp = D + (size_t)slot * 256;
    float d00 = Dp[x0i], d01 = Dp[x1i];
    float d10 = Dp[128 + x0i], d11 = Dp[128 + x1i];
    float u0 = 1.0f - wy, u1 = wy;
    float dv0 = u0 * d00 + u1 * d10;
    float dv1 = u0 * d01 + u1 * d11;
    float dot = (1.0f - wx) * dv0 + wx * dv1;

    const float* st0 = stats + (size_t)(b * 128 + x0i) * 8;
    const float* st1 = stats + (size_t)(b * 128 + x1i) * 8;
    float4 sa = *(const float4*)st0;
    float4 sb = *(const float4*)(st0 + 4);
    float4 sc = *(const float4*)st1;
    float a0 = u0 * u0, a1 = u0 * u1, a2 = u1 * u1;
    float nB0 = a0 * sa.x + 2.0f * a1 * sa.y + a2 * sa.z;
    float nB1 = a0 * sc.x + 2.0f * a1 * sc.y + a2 * sc.z;
    float cB  = a0 * sa.w + a1 * (sb.x + sb.y) + a2 * sb.z;
    float wx0 = 1.0f - wx;
    float nsq = wx0 * wx0 * nB0 + 2.0f * wx * wx0 * cB + wx * wx * nB1;
    float ln = dot / fmaxf(sqrtf(fmaxf(nsq, 0.0f)), 1e-12f);
    esum = __expf(ln * (1.0f / 0.07f) - MSHIFT);
  }
#pragma unroll
  for (int o = 32; o; o >>= 1) esum += __shfl_xor(esum, o, 64);
  if (lane == 0) atomicAdd(&S[p], esum);
}

// -------- MFMA l_q GEMM over compacted rows, fused exp2 epilogue --------
// block tile 64p; loops 3 chunks of 128n (grid.x=16 covers 6144 padded cols).
__global__ __launch_bounds__(256) void k_gemm_mfma(
    const _Float16* __restrict__ QTf,     // [NPIX][128]
    const _Float16* __restrict__ queueTf, // [6144][128], rows >=6000 zero
    const float2* __restrict__ qeb,       // [6144] (scale, bias); pad (0,-1000)
    float* __restrict__ S,
    const int* __restrict__ count, const int* __restrict__ list) {
  __shared__ float Srow[64];
  int tid = threadIdx.x;
  int cnt = *count;
  if ((int)(blockIdx.y * 64) >= cnt) return;
  int wave = tid >> 6;
  int lane = tid & 63;
  int quad = lane >> 4;
  int l16 = lane & 15;
  int wm = wave >> 1;
  int wn = wave & 1;
  int p0 = blockIdx.y * 64 + wm * 32;

  if (tid < 64) Srow[tid] = 0.0f;

  int prow[2];
#pragma unroll
  for (int mt = 0; mt < 2; mt++)
    prow[mt] = list[min(p0 + mt * 16 + l16, cnt - 1)];

  f16_8 Af[2][4];
#pragma unroll
  for (int mt = 0; mt < 2; mt++) {
    const _Float16* arow = QTf + (size_t)prow[mt] * CFM + quad * 8;
#pragma unroll
    for (int ks = 0; ks < 4; ks++)
      Af[mt][ks] = *(const f16_8*)(arow + ks * 32);
  }

  float rowsum[2][4] = {{0.0f,0.0f,0.0f,0.0f},{0.0f,0.0f,0.0f,0.0f}};

#pragma unroll
  for (int ic = 0; ic < 3; ic++) {
    int n0 = (blockIdx.x * 3 + ic) * 128 + wn * 64;

    f16_8 Bf[4][4];
    const _Float16* brow = queueTf + (size_t)(n0 + l16) * CFM + quad * 8;
#pragma unroll
    for (int nt = 0; nt < 4; nt++)
#pragma unroll
      for (int ks = 0; ks < 4; ks++)
        Bf[nt][ks] = *(const f16_8*)(brow + (size_t)nt * 16 * CFM + ks * 32);

    float2 qb[4];
#pragma unroll
    for (int nt = 0; nt < 4; nt++) qb[nt] = qeb[n0 + nt * 16 + l16];

    f32_4 acc[2][4];
#pragma unroll
    for (int mt = 0; mt < 2; mt++)
#pragma unroll
      for (int nt = 0; nt < 4; nt++)
        acc[mt][nt] = (f32_4){0.0f, 0.0f, 0.0f, 0.0f};

#pragma unroll
    for (int ks = 0; ks < 4; ks++)
#pragma unroll
      for (int mt = 0; mt < 2; mt++)
#pragma unroll
        for (int nt = 0; nt < 4; nt++)
          acc[mt][nt] = __builtin_amdgcn_mfma_f32_16x16x32_f16(Af[mt][ks], Bf[nt][ks], acc[mt][nt], 0, 0, 0);

#pragma unroll
    for (int nt = 0; nt < 4; nt++)
#pragma unroll
      for (int mt = 0; mt < 2; mt++)
#pragma unroll
        for (int r = 0; r < 4; r++)
          rowsum[mt][r] += exp2f(fmaf(acc[mt][nt][r], qb[nt].x, qb[nt].y));
  }

#pragma unroll
  for (int mt = 0; mt < 2; mt++)
#pragma unroll
    for (int r = 0; r < 4; r++) {
      float vv = rowsum[mt][r];
      vv += __shfl_xor(vv, 1);
      vv += __shfl_xor(vv, 2);
      vv += __shfl_xor(vv, 4);
      vv += __shfl_xor(vv, 8);
      rowsum[mt][r] = vv;
    }
  __syncthreads();
  if (l16 == 0) {
#pragma unroll
    for (int mt = 0; mt < 2; mt++)
#pragma unroll
      for (int r = 0; r < 4; r++)
        atomicAdd(&Srow[wm * 32 + mt * 16 + quad * 4 + r], rowsum[mt][r]);
  }
  __syncthreads();
  if (tid < 64) {
    int pr = blockIdx.y * 64 + tid;
    if (pr < cnt) atomicAdd(&S[list[pr]], Srow[tid]);
  }
}

__global__ __launch_bounds__(1024) void k_finalize(
    const float* __restrict__ S, const float* __restrict__ logit0,
    const float* __restrict__ maskArr, float* __restrict__ out) {
  int tid = threadIdx.x;
  const float cmask = logf(6061.0f);
  double acc = 0.0;
  for (int p = tid; p < NPIX; p += 1024) {
    float term = (maskArr[p] > 0.0f) ? (logf(S[p]) + MSHIFT - logit0[p]) : cmask;
    acc += (double)term;
  }
#pragma unroll
  for (int off = 32; off; off >>= 1) acc += __shfl_down(acc, off, 64);
  __shared__ double sd[16];
  if ((tid & 63) == 0) sd[tid >> 6] = acc;
  __syncthreads();
  if (tid == 0) {
    double tot = 0.0;
    for (int w = 0; w < 16; w++) tot += sd[w];
    out[0] = (float)(tot / (double)NPIX);
  }
}

extern "C" void kernel_launch(void* const* d_in, const int* in_sizes, int n_in,
                              void* d_out, int out_size, void* d_ws, size_t ws_size,
                              hipStream_t stream) {
  const float* ref   = (const float*)d_in[0];
  const float* tgt   = (const float*)d_in[1];
  const float* tl    = (const float*)d_in[2];
  const float* tr    = (const float*)d_in[3];
  const float* queue = (const float*)d_in[4];
  float* out = (float*)d_out;
  float* ws = (float*)d_ws;

  float2* qeb = (float2*)ws;                 // 6144 float2 -> 12288 floats
  float* S    = ws + 12288;                  // 16384
  float* lg0  = ws + 28672;                  // 16384
  float* mk   = ws + 45056;                  // 16384
  float* xr   = ws + 61440;                  // 16384 -> 77824
  int* count  = (int*)(ws + 77824);          // 1
  int* list   = (int*)(ws + 77840);          // 16384 -> 94224
  _Float16* QTf     = (_Float16*)(ws + 94464);    // NPIX*128 f16   (1048576 fl)
  _Float16* queueTf = (_Float16*)(ws + 1143040);  // 6144*128 f16   (393216 fl)
  _Float16* tgtTf   = (_Float16*)(ws + 1536256);  // NPIX*128 f16   (1048576 fl)
  _Float16* refTf   = (_Float16*)(ws + 2584832);  // NPIX*128 f16   (1048576 fl)
  float* stats = ws + 3633408;                    // 2048 -> 3635456
  float* D     = ws + 3635456;                    // NPIX*256 f32

  // JAX: k1, k2 = split(key(1234))
  uint32_t b0o0, b0o1, b1o0, b1o1;
  threefry2x32(0u, 1234u, 0u, 2u, &b0o0, &b0o1);
  threefry2x32(0u, 1234u, 1u, 3u, &b1o0, &b1o1);
  uint32_t k1a = b0o0, k1b = b1o0, k2a = b0o1, k2b = b1o1;

  k_transpose<<<dim3(HWFM / 32, CFM / 32, 4), dim3(32, 8), 0, stream>>>(ref, tgt, refTf, tgtTf);
  k_qtrans<<<dim3(KQP / 32, CFM / 32), dim3(32, 8), 0, stream>>>(queue, queueTf);
  k_qprep<<<dim3(KQP / 256), dim3(256), 0, stream>>>(queue, qeb);
  k_colstats<<<dim3(256), dim3(64), 0, stream>>>(tgtTf, stats);
  k_prelude<<<dim3(NPIX / 4), dim3(256), 0, stream>>>(tl, tr, refTf, tgtTf, QTf, S, lg0, mk, xr);
  k_compact<<<dim3(1), dim3(1024), 0, stream>>>(mk, count, list);
  k_dgemm<<<dim3(NPIX / 64), dim3(256), 0, stream>>>(QTf, tgtTf, D, count, list);
  k_negatives_lite<<<dim3(NPIX / 4), dim3(256), 0, stream>>>(D, stats, xr, S, count, list, k1a, k1b, k2a, k2b);
  k_gemm_mfma<<<dim3(16, NPIX / 64), dim3(256), 0, stream>>>(QTf, queueTf, qeb, S, count, list);
  k_finalize<<<dim3(1), dim3(1024), 0, stream>>>(S, lg0, mk, out);
}

// Round 10
// 163.687 us; speedup vs baseline: 1.0150x; 1.0150x over previous
//
#include <hip/hip_runtime.h>
#include <stdint.h>
#include <math.h>

#define HFM 64
#define WFM 128
#define CFM 128
#define BN 2
#define HWFM (HFM*WFM)          // 8192
#define NPIX (BN*HWFM)          // 16384
#define KQ 6000
#define KQP 6144                // padded to 48*128 (rows 6000..6143 zero)
#define NNEG 60
#define NE (NPIX*NNEG)          // 983040
#define EHALF_U 491520u
#define MSHIFT 15.0f
#define LOG2E 1.4426950408889634f

typedef _Float16 f16_8 __attribute__((ext_vector_type(8)));
typedef _Float16 f16_2 __attribute__((ext_vector_type(2)));
typedef float f32_4 __attribute__((ext_vector_type(4)));

// ---------------- JAX threefry2x32 (bit-exact) ----------------
__host__ __device__ __forceinline__ void threefry2x32(uint32_t k0, uint32_t k1,
                                                      uint32_t x0, uint32_t x1,
                                                      uint32_t* o0, uint32_t* o1) {
  uint32_t ks2 = k0 ^ k1 ^ 0x1BD11BDAu;
  x0 += k0; x1 += k1;
#define TFR(r) { x0 += x1; x1 = (x1 << (r)) | (x1 >> (32 - (r))); x1 ^= x0; }
  TFR(13) TFR(15) TFR(26) TFR(6)
  x0 += k1;  x1 += ks2 + 1u;
  TFR(17) TFR(29) TFR(16) TFR(24)
  x0 += ks2; x1 += k0 + 2u;
  TFR(13) TFR(15) TFR(26) TFR(6)
  x0 += k0;  x1 += k1 + 3u;
  TFR(17) TFR(29) TFR(16) TFR(24)
  x0 += k1;  x1 += ks2 + 4u;
  TFR(13) TFR(15) TFR(26) TFR(6)
  x0 += ks2; x1 += k0 + 5u;
#undef TFR
  *o0 = x0; *o1 = x1;
}

// grid_sample coordinate helper (reference op order)
__device__ __forceinline__ void gs_coord(float t, float halfdim, float maxc,
                                         int* i0, int* i1, float* w) {
  float g = 2.0f * t - 1.0f;
  float x = (g + 1.0f) * halfdim - 0.5f;
  x = fminf(fmaxf(x, 0.0f), maxc);
  float f = floorf(x);
  *i0 = (int)f;
  *w = x - f;
  *i1 = (int)fminf(f + 1.0f, maxc);
}

// ref [b,c,hw] -> refTf f16 [b,hw,c];  tgt [b,c,hw] -> tgtTf f16 [b,hw,c]
__global__ void k_transpose(const float* __restrict__ ref, const float* __restrict__ tgt,
                            _Float16* __restrict__ refTf, _Float16* __restrict__ tgtTf) {
  __shared__ float tile[32][33];
  int z = blockIdx.z;
  int arr = z >> 1, b = z & 1;
  const float* src = (arr == 0 ? ref : tgt) + (size_t)b * CFM * HWFM;
  _Float16* dst = (arr == 0 ? refTf : tgtTf) + (size_t)b * HWFM * CFM;
  int x0 = blockIdx.x * 32;   // hw
  int y0 = blockIdx.y * 32;   // c
  int tx = threadIdx.x, ty = threadIdx.y;
#pragma unroll
  for (int i = 0; i < 32; i += 8)
    tile[ty + i][tx] = src[(size_t)(y0 + ty + i) * HWFM + x0 + tx];
  __syncthreads();
#pragma unroll
  for (int i = 0; i < 32; i += 8)
    dst[(size_t)(x0 + ty + i) * CFM + (y0 + tx)] = (_Float16)tile[tx][ty + i];
}

// transpose queue [128][6000] fp32 -> [6144][128] f16 (rows 6000..6143 zero)
__global__ void k_qtrans(const float* __restrict__ queue, _Float16* __restrict__ queueTf) {
  __shared__ float tile[32][33];
  int n0 = blockIdx.x * 32;   // queue col
  int c0 = blockIdx.y * 32;   // channel
  int tx = threadIdx.x, ty = threadIdx.y;
#pragma unroll
  for (int i = 0; i < 32; i += 8) {
    int n = n0 + tx;
    tile[ty + i][tx] = (n < KQ) ? queue[(size_t)(c0 + ty + i) * KQ + n] : 0.0f;
  }
  __syncthreads();
#pragma unroll
  for (int i = 0; i < 32; i += 8)
    queueTf[(size_t)(n0 + ty + i) * CFM + (c0 + tx)] = (_Float16)tile[tx][ty + i];
}

// queue column exp-prep: qeb[n] = (qInv*log2e/T, -15*log2e); pad: (0, -1000)
__global__ void k_qprep(const float* __restrict__ queue, float2* __restrict__ qeb) {
  int k = blockIdx.x * 256 + threadIdx.x;
  if (k >= KQP) return;
  if (k >= KQ) { qeb[k] = make_float2(0.0f, -1000.0f); return; }
  float ss = 0.0f;
  for (int c = 0; c < CFM; c++) { float v = queue[c * KQ + k]; ss += v * v; }
  float qi = 1.0f / fmaxf(sqrtf(ss), 1e-12f);
  qeb[k] = make_float2(qi * (LOG2E / 0.07f), -MSHIFT * LOG2E);
}

// per-(batch,x) column stats over rows y=0,1 of tgtTf
__global__ __launch_bounds__(64) void k_colstats(const _Float16* __restrict__ tgtTf,
                                                 float* __restrict__ stats) {
  int b = blockIdx.x >> 7, x = blockIdx.x & 127;
  int xp = min(x + 1, 127);
  int lane = threadIdx.x;
  int c2 = lane * 2;
  int base = b * HWFM;
  f16_2 c0  = *(const f16_2*)(tgtTf + (size_t)(base + x) * CFM + c2);
  f16_2 c1  = *(const f16_2*)(tgtTf + (size_t)(base + WFM + x) * CFM + c2);
  f16_2 c0p = *(const f16_2*)(tgtTf + (size_t)(base + xp) * CFM + c2);
  f16_2 c1p = *(const f16_2*)(tgtTf + (size_t)(base + WFM + xp) * CFM + c2);
  float a0 = (float)c0[0], a1 = (float)c0[1];
  float b0 = (float)c1[0], b1 = (float)c1[1];
  float p0 = (float)c0p[0], p1 = (float)c0p[1];
  float q0 = (float)c1p[0], q1 = (float)c1p[1];
  float s[7];
  s[0] = a0 * a0 + a1 * a1;
  s[1] = a0 * b0 + a1 * b1;
  s[2] = b0 * b0 + b1 * b1;
  s[3] = a0 * p0 + a1 * p1;
  s[4] = a0 * q0 + a1 * q1;
  s[5] = b0 * p0 + b1 * p1;
  s[6] = b0 * q0 + b1 * q1;
#pragma unroll
  for (int o = 32; o; o >>= 1)
#pragma unroll
    for (int k = 0; k < 7; k++) s[k] += __shfl_xor(s[k], o, 64);
  if (lane == 0) {
    float* st = stats + (size_t)(b * 128 + x) * 8;
#pragma unroll
    for (int k = 0; k < 7; k++) st[k] = s[k];
    st[7] = 0.0f;
  }
}

// per pixel (wave-per-pixel): mask; if unmasked: fused query normalize,
// positive dot, l_pos, xr, S store.
__global__ __launch_bounds__(256) void k_prelude(
    const float* __restrict__ target_l, const float* __restrict__ target_r,
    const _Float16* __restrict__ refTf, const _Float16* __restrict__ tgtTf,
    _Float16* __restrict__ QTf,
    float* __restrict__ S, float* __restrict__ logit0,
    float* __restrict__ maskArr, float* __restrict__ xr) {
  int tid = threadIdx.x;
  int wave = tid >> 6, lane = tid & 63;
  int p = blockIdx.x * 4 + wave;
  int b = p >> 13;
  int rem = p & (HWFM - 1);
  int i = rem >> 7, j = rem & 127;
  const float stepx = 1.0f / 127.0f, stepy = 1.0f / 63.0f;
  float xb = (j == 127) ? 1.0f : j * stepx;
  float yb = (i == 63) ? 1.0f : i * stepy;
  const float* tl = target_l + (size_t)b * 256 * 512;
  const float* tr = target_r + (size_t)b * 256 * 512;

  int c2 = lane * 2;
  f16_2 q2 = *(const f16_2*)(refTf + (size_t)p * CFM + c2);

  float dl = tl[(4 * i) * 512 + 4 * j] * 0.25f;

  int y0i, y1i; float wy;
  gs_coord(yb, 32.0f, 63.0f, &y0i, &y1i, &wy);
  float t = xb - dl * (1.0f / 128.0f);
  int x0i, x1i; float wx;
  gs_coord(t, 64.0f, 127.0f, &x0i, &x1i, &wx);

  int bo = b * HWFM;
  f16_2 a2 = *(const f16_2*)(tgtTf + (size_t)(bo + y0i * WFM + x0i) * CFM + c2);
  f16_2 b2 = *(const f16_2*)(tgtTf + (size_t)(bo + y0i * WFM + x1i) * CFM + c2);
  f16_2 cc2 = *(const f16_2*)(tgtTf + (size_t)(bo + y1i * WFM + x0i) * CFM + c2);
  f16_2 d2 = *(const f16_2*)(tgtTf + (size_t)(bo + y1i * WFM + x1i) * CFM + c2);

  auto innerv = [&](int y, int x) -> float {
    float xbx = (x == 127) ? 1.0f : x * stepx;
    float drv = tr[(4 * y) * 512 + 4 * x] * 0.25f;
    float ti = xbx + drv * (1.0f / 128.0f);
    float g = 2.0f * ti - 1.0f;
    float ix2 = fminf(fmaxf((g + 1.0f) * 64.0f - 0.5f, 0.0f), 127.0f);
    float x0f = floorf(ix2);
    float wxp = ix2 - x0f;
    float x1f = fminf(x0f + 1.0f, 127.0f);
    return x0f * (1.0f - wxp) + x1f * wxp;
  };
  float v00 = innerv(y0i, x0i), v01 = innerv(y0i, x1i);
  float v10 = innerv(y1i, x0i), v11 = innerv(y1i, x1i);
  float l2r2l = v00 * (1.0f - wx) * (1.0f - wy) + v01 * wx * (1.0f - wy)
              + v10 * (1.0f - wx) * wy + v11 * wx * wy;
  bool masko = fabsf((float)j - l2r2l) < 3.0f;
  bool mk = masko && (dl > 0.0f) && (t >= 0.0f);
  if (lane == 0) maskArr[p] = mk ? 1.0f : 0.0f;
  if (!mk) return;

  float w00 = (1.0f - wx) * (1.0f - wy), w01 = wx * (1.0f - wy);
  float w10 = (1.0f - wx) * wy,          w11 = wx * wy;
  float q0 = (float)q2[0], q1 = (float)q2[1];
  float v0 = w00 * (float)a2[0] + w01 * (float)b2[0] + w10 * (float)cc2[0] + w11 * (float)d2[0];
  float v1 = w00 * (float)a2[1] + w01 * (float)b2[1] + w10 * (float)cc2[1] + w11 * (float)d2[1];

  float s0 = q0 * q0 + q1 * q1;
  float s1 = q0 * v0 + q1 * v1;
  float s2 = v0 * v0 + v1 * v1;
#pragma unroll
  for (int o = 32; o; o >>= 1) {
    s0 += __shfl_xor(s0, o, 64);
    s1 += __shfl_xor(s1, o, 64);
    s2 += __shfl_xor(s2, o, 64);
  }
  float inv = 1.0f / fmaxf(sqrtf(s0), 1e-12f);
  f16_2 qw; qw[0] = (_Float16)(q0 * inv); qw[1] = (_Float16)(q1 * inv);
  *(f16_2*)(QTf + (size_t)p * CFM + c2) = qw;
  if (lane == 0) {
    float lpos = (s1 * inv) / fmaxf(sqrtf(s2), 1e-12f);
    float lg0 = lpos / 0.07f;
    logit0[p] = lg0;
    xr[p] = t * 128.0f;
    S[p] = expf(lg0 - MSHIFT);
  }
}

// single-block ballot + prefix-scan compaction (ascending pixel order)
__global__ __launch_bounds__(1024) void k_compact(const float* __restrict__ maskArr,
                                                  int* __restrict__ count,
                                                  int* __restrict__ list) {
  int tid = threadIdx.x;
  int lane = tid & 63, wave = tid >> 6;
  int base_p = tid * 16;
  const float4* m4 = (const float4*)(maskArr + base_p);
  float4 v[4];
#pragma unroll
  for (int k = 0; k < 4; k++) v[k] = m4[k];
  unsigned int bits = 0;
#pragma unroll
  for (int k = 0; k < 4; k++) {
    if (v[k].x > 0.0f) bits |= 1u << (4 * k + 0);
    if (v[k].y > 0.0f) bits |= 1u << (4 * k + 1);
    if (v[k].z > 0.0f) bits |= 1u << (4 * k + 2);
    if (v[k].w > 0.0f) bits |= 1u << (4 * k + 3);
  }
  int m = __popc(bits);
  int scan = m;
#pragma unroll
  for (int off = 1; off < 64; off <<= 1) {
    int n = __shfl_up(scan, off, 64);
    if (lane >= off) scan += n;
  }
  __shared__ int wsum[16];
  if (lane == 63) wsum[wave] = scan;
  __syncthreads();
  int wbase = 0;
  for (int w = 0; w < wave; w++) wbase += wsum[w];
  int idx = wbase + scan - m;
#pragma unroll
  for (int k = 0; k < 16; k++) {
    if (bits & (1u << k)) list[idx++] = base_p + k;
  }
  if (tid == 1023) *count = idx;
}

// -------- D-GEMM: D[slot][x] = dot(C_y[x], q_slot), y=0 cols 0..127, y=1 128..255
// register double-buffered B across the 4 chunks.
__global__ __launch_bounds__(256, 2) void k_dgemm(
    const _Float16* __restrict__ QTf, const _Float16* __restrict__ tgtTf,
    float* __restrict__ D,
    const int* __restrict__ count, const int* __restrict__ list) {
  int tid = threadIdx.x;
  int cnt = *count;
  int pblk = blockIdx.x * 64;
  if (pblk >= cnt) return;
  int wave = tid >> 6, lane = tid & 63;
  int quad = lane >> 4, l16 = lane & 15;
  int wm = wave >> 1, wn = wave & 1;
  int p0 = pblk + wm * 32;

  __shared__ int pb[64];
  if (tid < 64) pb[tid] = list[min(pblk + tid, cnt - 1)] >> 13;
  __syncthreads();

  int prow[2];
#pragma unroll
  for (int mt = 0; mt < 2; mt++)
    prow[mt] = list[min(p0 + mt * 16 + l16, cnt - 1)];

  f16_8 Af[2][4];
#pragma unroll
  for (int mt = 0; mt < 2; mt++) {
    const _Float16* arow = QTf + (size_t)prow[mt] * CFM + quad * 8;
#pragma unroll
    for (int ks = 0; ks < 4; ks++)
      Af[mt][ks] = *(const f16_8*)(arow + ks * 32);
  }

  f16_8 Bf[2][4][4];
  // prologue: chunk 0 (rowbase 0)
  {
    const _Float16* brow = tgtTf + (size_t)(wn * 64 + l16) * CFM + quad * 8;
#pragma unroll
    for (int nt = 0; nt < 4; nt++)
#pragma unroll
      for (int ks = 0; ks < 4; ks++)
        Bf[0][nt][ks] = *(const f16_8*)(brow + (size_t)nt * 16 * CFM + ks * 32);
  }

#pragma unroll
  for (int ic = 0; ic < 4; ic++) {
    int cur = ic & 1, nxt = cur ^ 1;
    if (ic < 3) {
      int icn = ic + 1;
      int rowbase = (icn < 2) ? icn * 128 : (HWFM + (icn - 2) * 128);
      const _Float16* brow = tgtTf + (size_t)(rowbase + wn * 64 + l16) * CFM + quad * 8;
#pragma unroll
      for (int nt = 0; nt < 4; nt++)
#pragma unroll
        for (int ks = 0; ks < 4; ks++)
          Bf[nxt][nt][ks] = *(const f16_8*)(brow + (size_t)nt * 16 * CFM + ks * 32);
    }
    f32_4 acc[2][4];
#pragma unroll
    for (int mt = 0; mt < 2; mt++)
#pragma unroll
      for (int nt = 0; nt < 4; nt++)
        acc[mt][nt] = (f32_4){0.0f, 0.0f, 0.0f, 0.0f};
#pragma unroll
    for (int ks = 0; ks < 4; ks++)
#pragma unroll
      for (int mt = 0; mt < 2; mt++)
#pragma unroll
        for (int nt = 0; nt < 4; nt++)
          acc[mt][nt] = __builtin_amdgcn_mfma_f32_16x16x32_f16(Af[mt][ks], Bf[cur][nt][ks], acc[mt][nt], 0, 0, 0);

    int colbase = ic * 128;
#pragma unroll
    for (int mt = 0; mt < 2; mt++)
#pragma unroll
      for (int nt = 0; nt < 4; nt++)
#pragma unroll
        for (int r = 0; r < 4; r++) {
          int rowloc = wm * 32 + mt * 16 + quad * 4 + r;
          int col = colbase + wn * 64 + nt * 16 + l16;
          if ((col >> 8) == pb[rowloc])
            D[(size_t)(pblk + rowloc) * 256 + (col & 255)] = acc[mt][nt][r];
        }
  }
}

// -------- negatives: wave-per-pixel, scalar via D + stats decomposition ----
__global__ __launch_bounds__(256) void k_negatives_lite(
    const float* __restrict__ D, const float* __restrict__ stats,
    const float* __restrict__ xr, float* __restrict__ S,
    const int* __restrict__ count, const int* __restrict__ list,
    uint32_t k1a, uint32_t k1b, uint32_t k2a, uint32_t k2b) {
  int tid = threadIdx.x;
  int wave = tid >> 6, lane = tid & 63;
  int cnt = *count;
  int slot = blockIdx.x * 4 + wave;
  if (slot >= cnt) return;
  int p = list[slot];
  int b = p >> 13;
  float esum = 0.0f;
  if (lane < NNEG) {
    uint32_t e = (uint32_t)(p * NNEG + lane);
    uint32_t h0, h1;
    threefry2x32(k1a, k1b, e, e + (uint32_t)NE, &h0, &h1);
    uint32_t off = ((h0 % 24u) * 16u + (h1 % 24u)) % 24u;
    float mag = (float)(1u + off);
    uint32_t ub;
    {
      uint32_t a, bm;
      if (e < EHALF_U) { threefry2x32(k2a, k2b, e, e + EHALF_U, &a, &bm); ub = a; }
      else             { threefry2x32(k2a, k2b, e - EHALF_U, e, &a, &bm); ub = bm; }
    }
    float u = __uint_as_float((ub >> 9) | 0x3F800000u) - 1.0f;
    float sg = (u > 0.5f) ? 1.0f : ((u < 0.5f) ? -1.0f : 0.0f);

    float v = xr[p] + mag * sg;
    float r = fmodf(v, 128.0f);
    if (r < 0.0f) r += 128.0f;
    float fx = r * (1.0f / 128.0f);
    float fy = fx * (1.0f / 64.0f);
    int x0i, x1i, y0i, y1i; float wx, wy;
    gs_coord(fx, 64.0f, 127.0f, &x0i, &x1i, &wx);
    gs_coord(fy, 32.0f, 63.0f, &y0i, &y1i, &wy);

    const float* Dp = D + (size_t)slot * 256;
    float d00 = Dp[x0i], d01 = Dp[x1i];
    float d10 = Dp[128 + x0i], d11 = Dp[128 + x1i];
    float u0 = 1.0f - wy, u1 = wy;
    float dv0 = u0 * d00 + u1 * d10;
    float dv1 = u0 * d01 + u1 * d11;
    float dot = (1.0f - wx) * dv0 + wx * dv1;

    const float* st0 = stats + (size_t)(b * 128 + x0i) * 8;
    const float* st1 = stats + (size_t)(b * 128 + x1i) * 8;
    float4 sa = *(const float4*)st0;
    float4 sb = *(const float4*)(st0 + 4);
    float4 sc = *(const float4*)st1;
    float a0 = u0 * u0, a1 = u0 * u1, a2 = u1 * u1;
    float nB0 = a0 * sa.x + 2.0f * a1 * sa.y + a2 * sa.z;
    float nB1 = a0 * sc.x + 2.0f * a1 * sc.y + a2 * sc.z;
    float cB  = a0 * sa.w + a1 * (sb.x + sb.y) + a2 * sb.z;
    float wx0 = 1.0f - wx;
    float nsq = wx0 * wx0 * nB0 + 2.0f * wx * wx0 * cB + wx * wx * nB1;
    float ln = dot / fmaxf(sqrtf(fmaxf(nsq, 0.0f)), 1e-12f);
    esum = __expf(ln * (1.0f / 0.07f) - MSHIFT);
  }
#pragma unroll
  for (int o = 32; o; o >>= 1) esum += __shfl_xor(esum, o, 64);
  if (lane == 0) atomicAdd(&S[p], esum);
}

// -------- MFMA l_q GEMM over compacted rows, fused exp2 epilogue --------
// block tile 64p; 6 chunks of 128n (grid.x=8); register double-buffered B.
__global__ __launch_bounds__(256, 2) void k_gemm_mfma(
    const _Float16* __restrict__ QTf,     // [NPIX][128]
    const _Float16* __restrict__ queueTf, // [6144][128], rows >=6000 zero
    const float2* __restrict__ qeb,       // [6144] (scale, bias); pad (0,-1000)
    float* __restrict__ S,
    const int* __restrict__ count, const int* __restrict__ list) {
  __shared__ float Srow[64];
  int tid = threadIdx.x;
  int cnt = *count;
  if ((int)(blockIdx.y * 64) >= cnt) return;
  int wave = tid >> 6;
  int lane = tid & 63;
  int quad = lane >> 4;
  int l16 = lane & 15;
  int wm = wave >> 1;
  int wn = wave & 1;
  int p0 = blockIdx.y * 64 + wm * 32;

  if (tid < 64) Srow[tid] = 0.0f;

  int prow[2];
#pragma unroll
  for (int mt = 0; mt < 2; mt++)
    prow[mt] = list[min(p0 + mt * 16 + l16, cnt - 1)];

  f16_8 Af[2][4];
#pragma unroll
  for (int mt = 0; mt < 2; mt++) {
    const _Float16* arow = QTf + (size_t)prow[mt] * CFM + quad * 8;
#pragma unroll
    for (int ks = 0; ks < 4; ks++)
      Af[mt][ks] = *(const f16_8*)(arow + ks * 32);
  }

  float rowsum[2][4] = {{0.0f,0.0f,0.0f,0.0f},{0.0f,0.0f,0.0f,0.0f}};

  int nbase = blockIdx.x * 6 * 128 + wn * 64;
  f16_8 Bf[2][4][4];
  float2 qb[2][4];
  // prologue: chunk 0
  {
    const _Float16* brow = queueTf + (size_t)(nbase + l16) * CFM + quad * 8;
#pragma unroll
    for (int nt = 0; nt < 4; nt++) {
#pragma unroll
      for (int ks = 0; ks < 4; ks++)
        Bf[0][nt][ks] = *(const f16_8*)(brow + (size_t)nt * 16 * CFM + ks * 32);
      qb[0][nt] = qeb[nbase + nt * 16 + l16];
    }
  }

#pragma unroll
  for (int ic = 0; ic < 6; ic++) {
    int cur = ic & 1, nxt = cur ^ 1;
    if (ic < 5) {
      int n0 = nbase + (ic + 1) * 128;
      const _Float16* brow = queueTf + (size_t)(n0 + l16) * CFM + quad * 8;
#pragma unroll
      for (int nt = 0; nt < 4; nt++) {
#pragma unroll
        for (int ks = 0; ks < 4; ks++)
          Bf[nxt][nt][ks] = *(const f16_8*)(brow + (size_t)nt * 16 * CFM + ks * 32);
        qb[nxt][nt] = qeb[n0 + nt * 16 + l16];
      }
    }

    f32_4 acc[2][4];
#pragma unroll
    for (int mt = 0; mt < 2; mt++)
#pragma unroll
      for (int nt = 0; nt < 4; nt++)
        acc[mt][nt] = (f32_4){0.0f, 0.0f, 0.0f, 0.0f};

#pragma unroll
    for (int ks = 0; ks < 4; ks++)
#pragma unroll
      for (int mt = 0; mt < 2; mt++)
#pragma unroll
        for (int nt = 0; nt < 4; nt++)
          acc[mt][nt] = __builtin_amdgcn_mfma_f32_16x16x32_f16(Af[mt][ks], Bf[cur][nt][ks], acc[mt][nt], 0, 0, 0);

#pragma unroll
    for (int nt = 0; nt < 4; nt++)
#pragma unroll
      for (int mt = 0; mt < 2; mt++)
#pragma unroll
        for (int r = 0; r < 4; r++)
          rowsum[mt][r] += exp2f(fmaf(acc[mt][nt][r], qb[cur][nt].x, qb[cur][nt].y));
  }

#pragma unroll
  for (int mt = 0; mt < 2; mt++)
#pragma unroll
    for (int r = 0; r < 4; r++) {
      float vv = rowsum[mt][r];
      vv += __shfl_xor(vv, 1);
      vv += __shfl_xor(vv, 2);
      vv += __shfl_xor(vv, 4);
      vv += __shfl_xor(vv, 8);
      rowsum[mt][r] = vv;
    }
  __syncthreads();
  if (l16 == 0) {
#pragma unroll
    for (int mt = 0; mt < 2; mt++)
#pragma unroll
      for (int r = 0; r < 4; r++)
        atomicAdd(&Srow[wm * 32 + mt * 16 + quad * 4 + r], rowsum[mt][r]);
  }
  __syncthreads();
  if (tid < 64) {
    int pr = blockIdx.y * 64 + tid;
    if (pr < cnt) atomicAdd(&S[list[pr]], Srow[tid]);
  }
}

__global__ __launch_bounds__(1024) void k_finalize(
    const float* __restrict__ S, const float* __restrict__ logit0,
    const float* __restrict__ maskArr, float* __restrict__ out) {
  int tid = threadIdx.x;
  const float cmask = logf(6061.0f);
  double acc = 0.0;
  for (int p = tid; p < NPIX; p += 1024) {
    float term = (maskArr[p] > 0.0f) ? (logf(S[p]) + MSHIFT - logit0[p]) : cmask;
    acc += (double)term;
  }
#pragma unroll
  for (int off = 32; off; off >>= 1) acc += __shfl_down(acc, off, 64);
  __shared__ double sd[16];
  if ((tid & 63) == 0) sd[tid >> 6] = acc;
  __syncthreads();
  if (tid == 0) {
    double tot = 0.0;
    for (int w = 0; w < 16; w++) tot += sd[w];
    out[0] = (float)(tot / (double)NPIX);
  }
}

extern "C" void kernel_launch(void* const* d_in, const int* in_sizes, int n_in,
                              void* d_out, int out_size, void* d_ws, size_t ws_size,
                              hipStream_t stream) {
  const float* ref   = (const float*)d_in[0];
  const float* tgt   = (const float*)d_in[1];
  const float* tl    = (const float*)d_in[2];
  const float* tr    = (const float*)d_in[3];
  const float* queue = (const float*)d_in[4];
  float* out = (float*)d_out;
  float* ws = (float*)d_ws;

  float2* qeb = (float2*)ws;                 // 6144 float2 -> 12288 floats
  float* S    = ws + 12288;                  // 16384
  float* lg0  = ws + 28672;                  // 16384
  float* mk   = ws + 45056;                  // 16384
  float* xr   = ws + 61440;                  // 16384 -> 77824
  int* count  = (int*)(ws + 77824);          // 1
  int* list   = (int*)(ws + 77840);          // 16384 -> 94224
  _Float16* QTf     = (_Float16*)(ws + 94464);    // NPIX*128 f16   (1048576 fl)
  _Float16* queueTf = (_Float16*)(ws + 1143040);  // 6144*128 f16   (393216 fl)
  _Float16* tgtTf   = (_Float16*)(ws + 1536256);  // NPIX*128 f16   (1048576 fl)
  _Float16* refTf   = (_Float16*)(ws + 2584832);  // NPIX*128 f16   (1048576 fl)
  float* stats = ws + 3633408;                    // 2048 -> 3635456
  float* D     = ws + 3635456;                    // NPIX*256 f32

  // JAX: k1, k2 = split(key(1234))
  uint32_t b0o0, b0o1, b1o0, b1o1;
  threefry2x32(0u, 1234u, 0u, 2u, &b0o0, &b0o1);
  threefry2x32(0u, 1234u, 1u, 3u, &b1o0, &b1o1);
  uint32_t k1a = b0o0, k1b = b1o0, k2a = b0o1, k2b = b1o1;

  k_transpose<<<dim3(HWFM / 32, CFM / 32, 4), dim3(32, 8), 0, stream>>>(ref, tgt, refTf, tgtTf);
  k_qtrans<<<dim3(KQP / 32, CFM / 32), dim3(32, 8), 0, stream>>>(queue, queueTf);
  k_qprep<<<dim3(KQP / 256), dim3(256), 0, stream>>>(queue, qeb);
  k_colstats<<<dim3(256), dim3(64), 0, stream>>>(tgtTf, stats);
  k_prelude<<<dim3(NPIX / 4), dim3(256), 0, stream>>>(tl, tr, refTf, tgtTf, QTf, S, lg0, mk, xr);
  k_compact<<<dim3(1), dim3(1024), 0, stream>>>(mk, count, list);
  k_dgemm<<<dim3(NPIX / 64), dim3(256), 0, stream>>>(QTf, tgtTf, D, count, list);
  k_negatives_lite<<<dim3(NPIX / 4), dim3(256), 0, stream>>>(D, stats, xr, S, count, list, k1a, k1b, k2a, k2b);
  k_gemm_mfma<<<dim3(8, NPIX / 64), dim3(256), 0, stream>>>(QTf, queueTf, qeb, S, count, list);
  k_finalize<<<dim3(1), dim3(1024), 0, stream>>>(S, lg0, mk, out);
}

// Round 11
// 151.697 us; speedup vs baseline: 1.0952x; 1.0790x over previous
//
#include <hip/hip_runtime.h>
#include <stdint.h>
#include <math.h>

#define HFM 64
#define WFM 128
#define CFM 128
#define BN 2
#define HWFM (HFM*WFM)          // 8192
#define NPIX (BN*HWFM)          // 16384
#define KQ 6000
#define KQP 6144                // padded to 48*128 (rows 6000..6143 zero)
#define NNEG 60
#define NE (NPIX*NNEG)          // 983040
#define EHALF_U 491520u
#define MSHIFT 15.0f
#define LOG2E 1.4426950408889634f

typedef _Float16 f16_8 __attribute__((ext_vector_type(8)));
typedef _Float16 f16_2 __attribute__((ext_vector_type(2)));
typedef float f32_4 __attribute__((ext_vector_type(4)));

// ---------------- JAX threefry2x32 (bit-exact) ----------------
__host__ __device__ __forceinline__ void threefry2x32(uint32_t k0, uint32_t k1,
                                                      uint32_t x0, uint32_t x1,
                                                      uint32_t* o0, uint32_t* o1) {
  uint32_t ks2 = k0 ^ k1 ^ 0x1BD11BDAu;
  x0 += k0; x1 += k1;
#define TFR(r) { x0 += x1; x1 = (x1 << (r)) | (x1 >> (32 - (r))); x1 ^= x0; }
  TFR(13) TFR(15) TFR(26) TFR(6)
  x0 += k1;  x1 += ks2 + 1u;
  TFR(17) TFR(29) TFR(16) TFR(24)
  x0 += ks2; x1 += k0 + 2u;
  TFR(13) TFR(15) TFR(26) TFR(6)
  x0 += k0;  x1 += k1 + 3u;
  TFR(17) TFR(29) TFR(16) TFR(24)
  x0 += k1;  x1 += ks2 + 4u;
  TFR(13) TFR(15) TFR(26) TFR(6)
  x0 += ks2; x1 += k0 + 5u;
#undef TFR
  *o0 = x0; *o1 = x1;
}

// grid_sample coordinate helper (reference op order)
__device__ __forceinline__ void gs_coord(float t, float halfdim, float maxc,
                                         int* i0, int* i1, float* w) {
  float g = 2.0f * t - 1.0f;
  float x = (g + 1.0f) * halfdim - 0.5f;
  x = fminf(fmaxf(x, 0.0f), maxc);
  float f = floorf(x);
  *i0 = (int)f;
  *w = x - f;
  *i1 = (int)fminf(f + 1.0f, maxc);
}

// ================= k_A: transpose + qtrans + qprep + mask =================
// blocks [0,4096): feature transpose; [4096,4864): queue transpose;
// [4864,4888): qeb prep; [4888,4952): per-pixel mask (thread/pixel).
__global__ __launch_bounds__(256) void k_A(
    const float* __restrict__ ref, const float* __restrict__ tgt,
    const float* __restrict__ queue,
    const float* __restrict__ target_l, const float* __restrict__ target_r,
    _Float16* __restrict__ refTf, _Float16* __restrict__ tgtTf,
    _Float16* __restrict__ queueTf, float2* __restrict__ qeb,
    float* __restrict__ maskArr, float* __restrict__ xr) {
  __shared__ float tile[32][33];
  int blk = blockIdx.x;
  int tid = threadIdx.x;
  if (blk < 4096) {
    int z = blk >> 10, yb_ = (blk >> 8) & 3, xb_ = blk & 255;
    int arr = z >> 1, b = z & 1;
    const float* src = (arr == 0 ? ref : tgt) + (size_t)b * CFM * HWFM;
    _Float16* dst = (arr == 0 ? refTf : tgtTf) + (size_t)b * HWFM * CFM;
    int x0 = xb_ * 32, y0 = yb_ * 32;
    int tx = tid & 31, ty = tid >> 5;
#pragma unroll
    for (int i = 0; i < 32; i += 8)
      tile[ty + i][tx] = src[(size_t)(y0 + ty + i) * HWFM + x0 + tx];
    __syncthreads();
#pragma unroll
    for (int i = 0; i < 32; i += 8)
      dst[(size_t)(x0 + ty + i) * CFM + (y0 + tx)] = (_Float16)tile[tx][ty + i];
  } else if (blk < 4864) {
    int q = blk - 4096;
    int cy = q / 192, nx = q - cy * 192;
    int n0 = nx * 32, c0 = cy * 32;
    int tx = tid & 31, ty = tid >> 5;
#pragma unroll
    for (int i = 0; i < 32; i += 8) {
      int n = n0 + tx;
      tile[ty + i][tx] = (n < KQ) ? queue[(size_t)(c0 + ty + i) * KQ + n] : 0.0f;
    }
    __syncthreads();
#pragma unroll
    for (int i = 0; i < 32; i += 8)
      queueTf[(size_t)(n0 + ty + i) * CFM + (c0 + tx)] = (_Float16)tile[tx][ty + i];
  } else if (blk < 4888) {
    int k = (blk - 4864) * 256 + tid;
    if (k < KQP) {
      if (k >= KQ) { qeb[k] = make_float2(0.0f, -1000.0f); }
      else {
        float ss = 0.0f;
        for (int c = 0; c < CFM; c++) { float v = queue[c * KQ + k]; ss += v * v; }
        float qi = 1.0f / fmaxf(sqrtf(ss), 1e-12f);
        qeb[k] = make_float2(qi * (LOG2E / 0.07f), -MSHIFT * LOG2E);
      }
    }
  } else {
    // mask: one thread per pixel
    int p = (blk - 4888) * 256 + tid;
    int b = p >> 13;
    int rem = p & (HWFM - 1);
    int i = rem >> 7, j = rem & 127;
    const float stepx = 1.0f / 127.0f, stepy = 1.0f / 63.0f;
    float xb = (j == 127) ? 1.0f : j * stepx;
    float yb = (i == 63) ? 1.0f : i * stepy;
    const float* tl = target_l + (size_t)b * 256 * 512;
    const float* tr = target_r + (size_t)b * 256 * 512;
    float dl = tl[(4 * i) * 512 + 4 * j] * 0.25f;
    int y0i, y1i; float wy;
    gs_coord(yb, 32.0f, 63.0f, &y0i, &y1i, &wy);
    float t = xb - dl * (1.0f / 128.0f);
    int x0i, x1i; float wx;
    gs_coord(t, 64.0f, 127.0f, &x0i, &x1i, &wx);
    auto innerv = [&](int y, int x) -> float {
      float xbx = (x == 127) ? 1.0f : x * stepx;
      float drv = tr[(4 * y) * 512 + 4 * x] * 0.25f;
      float ti = xbx + drv * (1.0f / 128.0f);
      float g = 2.0f * ti - 1.0f;
      float ix2 = fminf(fmaxf((g + 1.0f) * 64.0f - 0.5f, 0.0f), 127.0f);
      float x0f = floorf(ix2);
      float wxp = ix2 - x0f;
      float x1f = fminf(x0f + 1.0f, 127.0f);
      return x0f * (1.0f - wxp) + x1f * wxp;
    };
    float v00 = innerv(y0i, x0i), v01 = innerv(y0i, x1i);
    float v10 = innerv(y1i, x0i), v11 = innerv(y1i, x1i);
    float l2r2l = v00 * (1.0f - wx) * (1.0f - wy) + v01 * wx * (1.0f - wy)
                + v10 * (1.0f - wx) * wy + v11 * wx * wy;
    bool masko = fabsf((float)j - l2r2l) < 3.0f;
    bool mk = masko && (dl > 0.0f) && (t >= 0.0f);
    maskArr[p] = mk ? 1.0f : 0.0f;
    xr[p] = t * 128.0f;   // exact: t*2^7
  }
}

// ================= k_B: colstats + prelude2 + compact =================
// blocks [0,64): colstats (4 x-cols each); [64,4160): prelude2 (4 px/block);
// block 4160: compaction.
__global__ __launch_bounds__(256) void k_B(
    const _Float16* __restrict__ refTf, const _Float16* __restrict__ tgtTf,
    _Float16* __restrict__ QTf, float* __restrict__ stats,
    const float* __restrict__ maskArr, const float* __restrict__ xr,
    float* __restrict__ S, float* __restrict__ logit0,
    int* __restrict__ count, int* __restrict__ list) {
  __shared__ int wsum[4];
  int blk = blockIdx.x;
  int tid = threadIdx.x;
  int lane = tid & 63;
  if (blk < 64) {
    // colstats: sub-wave per x
    int sub = tid >> 6;
    int xg = blk * 4 + sub;
    int b = xg >> 7, x = xg & 127;
    int xp = min(x + 1, 127);
    int c2 = lane * 2;
    int base = b * HWFM;
    f16_2 c0  = *(const f16_2*)(tgtTf + (size_t)(base + x) * CFM + c2);
    f16_2 c1  = *(const f16_2*)(tgtTf + (size_t)(base + WFM + x) * CFM + c2);
    f16_2 c0p = *(const f16_2*)(tgtTf + (size_t)(base + xp) * CFM + c2);
    f16_2 c1p = *(const f16_2*)(tgtTf + (size_t)(base + WFM + xp) * CFM + c2);
    float a0 = (float)c0[0], a1 = (float)c0[1];
    float b0 = (float)c1[0], b1 = (float)c1[1];
    float p0 = (float)c0p[0], p1 = (float)c0p[1];
    float q0 = (float)c1p[0], q1 = (float)c1p[1];
    float s[7];
    s[0] = a0 * a0 + a1 * a1;
    s[1] = a0 * b0 + a1 * b1;
    s[2] = b0 * b0 + b1 * b1;
    s[3] = a0 * p0 + a1 * p1;
    s[4] = a0 * q0 + a1 * q1;
    s[5] = b0 * p0 + b1 * p1;
    s[6] = b0 * q0 + b1 * q1;
#pragma unroll
    for (int o = 32; o; o >>= 1)
#pragma unroll
      for (int k = 0; k < 7; k++) s[k] += __shfl_xor(s[k], o, 64);
    if (lane == 0) {
      float* st = stats + (size_t)xg * 8;
#pragma unroll
      for (int k = 0; k < 7; k++) st[k] = s[k];
      st[7] = 0.0f;
    }
  } else if (blk < 4160) {
    // prelude2: wave per pixel, only unmasked do work
    int wave = tid >> 6;
    int p = (blk - 64) * 4 + wave;
    float mk = maskArr[p];
    if (mk == 0.0f) return;
    int b = p >> 13;
    int rem = p & (HWFM - 1);
    int i = rem >> 7;
    const float stepy = 1.0f / 63.0f;
    float yb = (i == 63) ? 1.0f : i * stepy;
    float t = xr[p] * (1.0f / 128.0f);   // exact recovery
    int y0i, y1i; float wy;
    gs_coord(yb, 32.0f, 63.0f, &y0i, &y1i, &wy);
    int x0i, x1i; float wx;
    gs_coord(t, 64.0f, 127.0f, &x0i, &x1i, &wx);

    int c2 = lane * 2;
    f16_2 q2 = *(const f16_2*)(refTf + (size_t)p * CFM + c2);
    int bo = b * HWFM;
    f16_2 a2 = *(const f16_2*)(tgtTf + (size_t)(bo + y0i * WFM + x0i) * CFM + c2);
    f16_2 b2 = *(const f16_2*)(tgtTf + (size_t)(bo + y0i * WFM + x1i) * CFM + c2);
    f16_2 cc2 = *(const f16_2*)(tgtTf + (size_t)(bo + y1i * WFM + x0i) * CFM + c2);
    f16_2 d2 = *(const f16_2*)(tgtTf + (size_t)(bo + y1i * WFM + x1i) * CFM + c2);

    float w00 = (1.0f - wx) * (1.0f - wy), w01 = wx * (1.0f - wy);
    float w10 = (1.0f - wx) * wy,          w11 = wx * wy;
    float q0 = (float)q2[0], q1 = (float)q2[1];
    float v0 = w00 * (float)a2[0] + w01 * (float)b2[0] + w10 * (float)cc2[0] + w11 * (float)d2[0];
    float v1 = w00 * (float)a2[1] + w01 * (float)b2[1] + w10 * (float)cc2[1] + w11 * (float)d2[1];

    float s0 = q0 * q0 + q1 * q1;
    float s1 = q0 * v0 + q1 * v1;
    float s2 = v0 * v0 + v1 * v1;
#pragma unroll
    for (int o = 32; o; o >>= 1) {
      s0 += __shfl_xor(s0, o, 64);
      s1 += __shfl_xor(s1, o, 64);
      s2 += __shfl_xor(s2, o, 64);
    }
    float inv = 1.0f / fmaxf(sqrtf(s0), 1e-12f);
    f16_2 qw; qw[0] = (_Float16)(q0 * inv); qw[1] = (_Float16)(q1 * inv);
    *(f16_2*)(QTf + (size_t)p * CFM + c2) = qw;
    if (lane == 0) {
      float lpos = (s1 * inv) / fmaxf(sqrtf(s2), 1e-12f);
      float lg0 = lpos / 0.07f;
      logit0[p] = lg0;
      S[p] = expf(lg0 - MSHIFT);
    }
  } else {
    // compact: single block, thread handles 64 consecutive pixels
    int wave = tid >> 6;
    int base_p = tid * 64;
    unsigned long long bits = 0ull;
    const float4* m4 = (const float4*)(maskArr + base_p);
#pragma unroll
    for (int k = 0; k < 16; k++) {
      float4 v = m4[k];
      if (v.x > 0.0f) bits |= 1ull << (4 * k + 0);
      if (v.y > 0.0f) bits |= 1ull << (4 * k + 1);
      if (v.z > 0.0f) bits |= 1ull << (4 * k + 2);
      if (v.w > 0.0f) bits |= 1ull << (4 * k + 3);
    }
    int m = __popcll(bits);
    int scan = m;
#pragma unroll
    for (int off = 1; off < 64; off <<= 1) {
      int n = __shfl_up(scan, off, 64);
      if (lane >= off) scan += n;
    }
    if (lane == 63) wsum[wave] = scan;
    __syncthreads();
    int wbase = 0;
    for (int w = 0; w < wave; w++) wbase += wsum[w];
    int idx = wbase + scan - m;
    for (int k = 0; k < 64; k++) {
      if ((bits >> k) & 1ull) list[idx++] = base_p + k;
    }
    if (tid == 255) *count = idx;
  }
}

// ======== k_gemmD: l_q MFMA GEMM (6 chunks, fused exp2 epilogue) ========
// plus fused D-GEMM chunk on x-blocks 0..3 (D[slot][x] decomposition table).
__global__ __launch_bounds__(256) void k_gemmD(
    const _Float16* __restrict__ QTf,     // [NPIX][128]
    const _Float16* __restrict__ queueTf, // [6144][128]
    const _Float16* __restrict__ tgtTf,   // [NPIX][128]
    const float2* __restrict__ qeb,       // [6144]
    float* __restrict__ S, float* __restrict__ D,
    const int* __restrict__ count, const int* __restrict__ list) {
  __shared__ float Srow[64];
  __shared__ int pb[64];
  int tid = threadIdx.x;
  int cnt = *count;
  int pblk = blockIdx.y * 64;
  if (pblk >= cnt) return;
  int wave = tid >> 6;
  int lane = tid & 63;
  int quad = lane >> 4;
  int l16 = lane & 15;
  int wm = wave >> 1;
  int wn = wave & 1;
  int p0 = pblk + wm * 32;

  if (tid < 64) {
    Srow[tid] = 0.0f;
    pb[tid] = list[min(pblk + tid, cnt - 1)] >> 13;
  }
  __syncthreads();

  int prow[2];
#pragma unroll
  for (int mt = 0; mt < 2; mt++)
    prow[mt] = list[min(p0 + mt * 16 + l16, cnt - 1)];

  f16_8 Af[2][4];
#pragma unroll
  for (int mt = 0; mt < 2; mt++) {
    const _Float16* arow = QTf + (size_t)prow[mt] * CFM + quad * 8;
#pragma unroll
    for (int ks = 0; ks < 4; ks++)
      Af[mt][ks] = *(const f16_8*)(arow + ks * 32);
  }

  // ---- fused D chunk (x-blocks 0..3 only) ----
  if (blockIdx.x < 4) {
    int ic2 = blockIdx.x;
    int colbase = ic2 * 128;
    int rowbase = (ic2 < 2) ? ic2 * 128 : (HWFM + (ic2 - 2) * 128);
    f16_8 Bf[4][4];
    const _Float16* brow = tgtTf + (size_t)(rowbase + wn * 64 + l16) * CFM + quad * 8;
#pragma unroll
    for (int nt = 0; nt < 4; nt++)
#pragma unroll
      for (int ks = 0; ks < 4; ks++)
        Bf[nt][ks] = *(const f16_8*)(brow + (size_t)nt * 16 * CFM + ks * 32);
    f32_4 acc[2][4];
#pragma unroll
    for (int mt = 0; mt < 2; mt++)
#pragma unroll
      for (int nt = 0; nt < 4; nt++)
        acc[mt][nt] = (f32_4){0.0f, 0.0f, 0.0f, 0.0f};
#pragma unroll
    for (int ks = 0; ks < 4; ks++)
#pragma unroll
      for (int mt = 0; mt < 2; mt++)
#pragma unroll
        for (int nt = 0; nt < 4; nt++)
          acc[mt][nt] = __builtin_amdgcn_mfma_f32_16x16x32_f16(Af[mt][ks], Bf[nt][ks], acc[mt][nt], 0, 0, 0);
#pragma unroll
    for (int mt = 0; mt < 2; mt++)
#pragma unroll
      for (int nt = 0; nt < 4; nt++)
#pragma unroll
        for (int r = 0; r < 4; r++) {
          int rowloc = wm * 32 + mt * 16 + quad * 4 + r;
          int col = colbase + wn * 64 + nt * 16 + l16;
          if ((col >> 8) == pb[rowloc])
            D[(size_t)(pblk + rowloc) * 256 + (col & 255)] = acc[mt][nt][r];
        }
  }

  // ---- l_q chunks ----
  float rowsum[2][4] = {{0.0f,0.0f,0.0f,0.0f},{0.0f,0.0f,0.0f,0.0f}};
#pragma unroll
  for (int ic = 0; ic < 6; ic++) {
    int n0 = (blockIdx.x * 6 + ic) * 128 + wn * 64;

    f16_8 Bf[4][4];
    const _Float16* brow = queueTf + (size_t)(n0 + l16) * CFM + quad * 8;
#pragma unroll
    for (int nt = 0; nt < 4; nt++)
#pragma unroll
      for (int ks = 0; ks < 4; ks++)
        Bf[nt][ks] = *(const f16_8*)(brow + (size_t)nt * 16 * CFM + ks * 32);

    float2 qb[4];
#pragma unroll
    for (int nt = 0; nt < 4; nt++) qb[nt] = qeb[n0 + nt * 16 + l16];

    f32_4 acc[2][4];
#pragma unroll
    for (int mt = 0; mt < 2; mt++)
#pragma unroll
      for (int nt = 0; nt < 4; nt++)
        acc[mt][nt] = (f32_4){0.0f, 0.0f, 0.0f, 0.0f};

#pragma unroll
    for (int ks = 0; ks < 4; ks++)
#pragma unroll
      for (int mt = 0; mt < 2; mt++)
#pragma unroll
        for (int nt = 0; nt < 4; nt++)
          acc[mt][nt] = __builtin_amdgcn_mfma_f32_16x16x32_f16(Af[mt][ks], Bf[nt][ks], acc[mt][nt], 0, 0, 0);

#pragma unroll
    for (int nt = 0; nt < 4; nt++)
#pragma unroll
      for (int mt = 0; mt < 2; mt++)
#pragma unroll
        for (int r = 0; r < 4; r++)
          rowsum[mt][r] += exp2f(fmaf(acc[mt][nt][r], qb[nt].x, qb[nt].y));
  }

#pragma unroll
  for (int mt = 0; mt < 2; mt++)
#pragma unroll
    for (int r = 0; r < 4; r++) {
      float vv = rowsum[mt][r];
      vv += __shfl_xor(vv, 1);
      vv += __shfl_xor(vv, 2);
      vv += __shfl_xor(vv, 4);
      vv += __shfl_xor(vv, 8);
      rowsum[mt][r] = vv;
    }
  __syncthreads();
  if (l16 == 0) {
#pragma unroll
    for (int mt = 0; mt < 2; mt++)
#pragma unroll
      for (int r = 0; r < 4; r++)
        atomicAdd(&Srow[wm * 32 + mt * 16 + quad * 4 + r], rowsum[mt][r]);
  }
  __syncthreads();
  if (tid < 64) {
    int pr = pblk + tid;
    if (pr < cnt) atomicAdd(&S[list[pr]], Srow[tid]);
  }
}

// -------- negatives: wave-per-pixel, scalar via D + stats decomposition ----
__global__ __launch_bounds__(256) void k_negatives_lite(
    const float* __restrict__ D, const float* __restrict__ stats,
    const float* __restrict__ xr, float* __restrict__ S,
    const int* __restrict__ count, const int* __restrict__ list,
    uint32_t k1a, uint32_t k1b, uint32_t k2a, uint32_t k2b) {
  int tid = threadIdx.x;
  int wave = tid >> 6, lane = tid & 63;
  int cnt = *count;
  int slot = blockIdx.x * 4 + wave;
  if (slot >= cnt) return;
  int p = list[slot];
  int b = p >> 13;
  float esum = 0.0f;
  if (lane < NNEG) {
    uint32_t e = (uint32_t)(p * NNEG + lane);
    uint32_t h0, h1;
    threefry2x32(k1a, k1b, e, e + (uint32_t)NE, &h0, &h1);
    uint32_t off = ((h0 % 24u) * 16u + (h1 % 24u)) % 24u;
    float mag = (float)(1u + off);
    uint32_t ub;
    {
      uint32_t a, bm;
      if (e < EHALF_U) { threefry2x32(k2a, k2b, e, e + EHALF_U, &a, &bm); ub = a; }
      else             { threefry2x32(k2a, k2b, e - EHALF_U, e, &a, &bm); ub = bm; }
    }
    float u = __uint_as_float((ub >> 9) | 0x3F800000u) - 1.0f;
    float sg = (u > 0.5f) ? 1.0f : ((u < 0.5f) ? -1.0f : 0.0f);

    float v = xr[p] + mag * sg;
    float r = fmodf(v, 128.0f);
    if (r < 0.0f) r += 128.0f;
    float fx = r * (1.0f / 128.0f);
    float fy = fx * (1.0f / 64.0f);
    int x0i, x1i, y0i, y1i; float wx, wy;
    gs_coord(fx, 64.0f, 127.0f, &x0i, &x1i, &wx);
    gs_coord(fy, 32.0f, 63.0f, &y0i, &y1i, &wy);

    const float* Dp = D + (size_t)slot * 256;
    float d00 = Dp[x0i], d01 = Dp[x1i];
    float d10 = Dp[128 + x0i], d11 = Dp[128 + x1i];
    float u0 = 1.0f - wy, u1 = wy;
    float dv0 = u0 * d00 + u1 * d10;
    float dv1 = u0 * d01 + u1 * d11;
    float dot = (1.0f - wx) * dv0 + wx * dv1;

    const float* st0 = stats + (size_t)(b * 128 + x0i) * 8;
    const float* st1 = stats + (size_t)(b * 128 + x1i) * 8;
    float4 sa = *(const float4*)st0;
    float4 sb = *(const float4*)(st0 + 4);
    float4 sc = *(const float4*)st1;
    float a0 = u0 * u0, a1 = u0 * u1, a2 = u1 * u1;
    float nB0 = a0 * sa.x + 2.0f * a1 * sa.y + a2 * sa.z;
    float nB1 = a0 * sc.x + 2.0f * a1 * sc.y + a2 * sc.z;
    float cB  = a0 * sa.w + a1 * (sb.x + sb.y) + a2 * sb.z;
    float wx0 = 1.0f - wx;
    float nsq = wx0 * wx0 * nB0 + 2.0f * wx * wx0 * cB + wx * wx * nB1;
    float ln = dot / fmaxf(sqrtf(fmaxf(nsq, 0.0f)), 1e-12f);
    esum = __expf(ln * (1.0f / 0.07f) - MSHIFT);
  }
#pragma unroll
  for (int o = 32; o; o >>= 1) esum += __shfl_xor(esum, o, 64);
  if (lane == 0) atomicAdd(&S[p], esum);
}

__global__ __launch_bounds__(1024) void k_finalize(
    const float* __restrict__ S, const float* __restrict__ logit0,
    const float* __restrict__ maskArr, float* __restrict__ out) {
  int tid = threadIdx.x;
  const float cmask = logf(6061.0f);
  double acc = 0.0;
  for (int p = tid; p < NPIX; p += 1024) {
    float term = (maskArr[p] > 0.0f) ? (logf(S[p]) + MSHIFT - logit0[p]) : cmask;
    acc += (double)term;
  }
#pragma unroll
  for (int off = 32; off; off >>= 1) acc += __shfl_down(acc, off, 64);
  __shared__ double sd[16];
  if ((tid & 63) == 0) sd[tid >> 6] = acc;
  __syncthreads();
  if (tid == 0) {
    double tot = 0.0;
    for (int w = 0; w < 16; w++) tot += sd[w];
    out[0] = (float)(tot / (double)NPIX);
  }
}

extern "C" void kernel_launch(void* const* d_in, const int* in_sizes, int n_in,
                              void* d_out, int out_size, void* d_ws, size_t ws_size,
                              hipStream_t stream) {
  const float* ref   = (const float*)d_in[0];
  const float* tgt   = (const float*)d_in[1];
  const float* tl    = (const float*)d_in[2];
  const float* tr    = (const float*)d_in[3];
  const float* queue = (const float*)d_in[4];
  float* out = (float*)d_out;
  float* ws = (float*)d_ws;

  float2* qeb = (float2*)ws;                 // 6144 float2 -> 12288 floats
  float* S    = ws + 12288;                  // 16384
  float* lg0  = ws + 28672;                  // 16384
  float* mk   = ws + 45056;                  // 16384
  float* xr   = ws + 61440;                  // 16384 -> 77824
  int* count  = (int*)(ws + 77824);          // 1
  int* list   = (int*)(ws + 77840);          // 16384 -> 94224
  _Float16* QTf     = (_Float16*)(ws + 94464);    // NPIX*128 f16
  _Float16* queueTf = (_Float16*)(ws + 1143040);  // 6144*128 f16
  _Float16* tgtTf   = (_Float16*)(ws + 1536256);  // NPIX*128 f16
  _Float16* refTf   = (_Float16*)(ws + 2584832);  // NPIX*128 f16
  float* stats = ws + 3633408;                    // 2048
  float* D     = ws + 3635456;                    // NPIX*256 f32

  // JAX: k1, k2 = split(key(1234))
  uint32_t b0o0, b0o1, b1o0, b1o1;
  threefry2x32(0u, 1234u, 0u, 2u, &b0o0, &b0o1);
  threefry2x32(0u, 1234u, 1u, 3u, &b1o0, &b1o1);
  uint32_t k1a = b0o0, k1b = b1o0, k2a = b0o1, k2b = b1o1;

  k_A<<<dim3(4952), dim3(256), 0, stream>>>(ref, tgt, queue, tl, tr,
                                            refTf, tgtTf, queueTf, qeb, mk, xr);
  k_B<<<dim3(4161), dim3(256), 0, stream>>>(refTf, tgtTf, QTf, stats,
                                            mk, xr, S, lg0, count, list);
  k_gemmD<<<dim3(8, NPIX / 64), dim3(256), 0, stream>>>(QTf, queueTf, tgtTf, qeb,
                                                        S, D, count, list);
  k_negatives_lite<<<dim3(NPIX / 4), dim3(256), 0, stream>>>(D, stats, xr, S, count, list,
                                                             k1a, k1b, k2a, k2b);
  k_finalize<<<dim3(1), dim3(1024), 0, stream>>>(S, lg0, mk, out);
}

// Round 12
// 149.706 us; speedup vs baseline: 1.1098x; 1.0133x over previous
//
#include <hip/hip_runtime.h>
#include <stdint.h>
#include <math.h>

#define HFM 64
#define WFM 128
#define CFM 128
#define BN 2
#define HWFM (HFM*WFM)          // 8192
#define NPIX (BN*HWFM)          // 16384
#define KQ 6000
#define KQP 6144                // padded to 48*128 (rows 6000..6143 zero)
#define NNEG 60
#define NE (NPIX*NNEG)          // 983040
#define EHALF_U 491520u
#define MSHIFT 15.0f
#define LOG2E 1.4426950408889634f
#define BSTRIDE 136             // LDS row stride in f16 (272 B: 16B-aligned, breaks bank pow2)

typedef _Float16 f16_8 __attribute__((ext_vector_type(8)));
typedef _Float16 f16_2 __attribute__((ext_vector_type(2)));
typedef float f32_4 __attribute__((ext_vector_type(4)));

// ---------------- JAX threefry2x32 (bit-exact) ----------------
__host__ __device__ __forceinline__ void threefry2x32(uint32_t k0, uint32_t k1,
                                                      uint32_t x0, uint32_t x1,
                                                      uint32_t* o0, uint32_t* o1) {
  uint32_t ks2 = k0 ^ k1 ^ 0x1BD11BDAu;
  x0 += k0; x1 += k1;
#define TFR(r) { x0 += x1; x1 = (x1 << (r)) | (x1 >> (32 - (r))); x1 ^= x0; }
  TFR(13) TFR(15) TFR(26) TFR(6)
  x0 += k1;  x1 += ks2 + 1u;
  TFR(17) TFR(29) TFR(16) TFR(24)
  x0 += ks2; x1 += k0 + 2u;
  TFR(13) TFR(15) TFR(26) TFR(6)
  x0 += k0;  x1 += k1 + 3u;
  TFR(17) TFR(29) TFR(16) TFR(24)
  x0 += k1;  x1 += ks2 + 4u;
  TFR(13) TFR(15) TFR(26) TFR(6)
  x0 += ks2; x1 += k0 + 5u;
#undef TFR
  *o0 = x0; *o1 = x1;
}

// grid_sample coordinate helper (reference op order)
__device__ __forceinline__ void gs_coord(float t, float halfdim, float maxc,
                                         int* i0, int* i1, float* w) {
  float g = 2.0f * t - 1.0f;
  float x = (g + 1.0f) * halfdim - 0.5f;
  x = fminf(fmaxf(x, 0.0f), maxc);
  float f = floorf(x);
  *i0 = (int)f;
  *w = x - f;
  *i1 = (int)fminf(f + 1.0f, maxc);
}

// ================= k_A: transpose + qtrans + qprep + mask =================
__global__ __launch_bounds__(256) void k_A(
    const float* __restrict__ ref, const float* __restrict__ tgt,
    const float* __restrict__ queue,
    const float* __restrict__ target_l, const float* __restrict__ target_r,
    _Float16* __restrict__ refTf, _Float16* __restrict__ tgtTf,
    _Float16* __restrict__ queueTf, float2* __restrict__ qeb,
    float* __restrict__ maskArr, float* __restrict__ xr) {
  __shared__ float tile[32][33];
  int blk = blockIdx.x;
  int tid = threadIdx.x;
  if (blk < 4096) {
    int z = blk >> 10, yb_ = (blk >> 8) & 3, xb_ = blk & 255;
    int arr = z >> 1, b = z & 1;
    const float* src = (arr == 0 ? ref : tgt) + (size_t)b * CFM * HWFM;
    _Float16* dst = (arr == 0 ? refTf : tgtTf) + (size_t)b * HWFM * CFM;
    int x0 = xb_ * 32, y0 = yb_ * 32;
    int tx = tid & 31, ty = tid >> 5;
#pragma unroll
    for (int i = 0; i < 32; i += 8)
      tile[ty + i][tx] = src[(size_t)(y0 + ty + i) * HWFM + x0 + tx];
    __syncthreads();
#pragma unroll
    for (int i = 0; i < 32; i += 8)
      dst[(size_t)(x0 + ty + i) * CFM + (y0 + tx)] = (_Float16)tile[tx][ty + i];
  } else if (blk < 4864) {
    int q = blk - 4096;
    int cy = q / 192, nx = q - cy * 192;
    int n0 = nx * 32, c0 = cy * 32;
    int tx = tid & 31, ty = tid >> 5;
#pragma unroll
    for (int i = 0; i < 32; i += 8) {
      int n = n0 + tx;
      tile[ty + i][tx] = (n < KQ) ? queue[(size_t)(c0 + ty + i) * KQ + n] : 0.0f;
    }
    __syncthreads();
#pragma unroll
    for (int i = 0; i < 32; i += 8)
      queueTf[(size_t)(n0 + ty + i) * CFM + (c0 + tx)] = (_Float16)tile[tx][ty + i];
  } else if (blk < 4888) {
    int k = (blk - 4864) * 256 + tid;
    if (k < KQP) {
      if (k >= KQ) { qeb[k] = make_float2(0.0f, -1000.0f); }
      else {
        float ss = 0.0f;
        for (int c = 0; c < CFM; c++) { float v = queue[c * KQ + k]; ss += v * v; }
        float qi = 1.0f / fmaxf(sqrtf(ss), 1e-12f);
        qeb[k] = make_float2(qi * (LOG2E / 0.07f), -MSHIFT * LOG2E);
      }
    }
  } else {
    // mask: one thread per pixel
    int p = (blk - 4888) * 256 + tid;
    int b = p >> 13;
    int rem = p & (HWFM - 1);
    int i = rem >> 7, j = rem & 127;
    const float stepx = 1.0f / 127.0f, stepy = 1.0f / 63.0f;
    float xb = (j == 127) ? 1.0f : j * stepx;
    float yb = (i == 63) ? 1.0f : i * stepy;
    const float* tl = target_l + (size_t)b * 256 * 512;
    const float* tr = target_r + (size_t)b * 256 * 512;
    float dl = tl[(4 * i) * 512 + 4 * j] * 0.25f;
    int y0i, y1i; float wy;
    gs_coord(yb, 32.0f, 63.0f, &y0i, &y1i, &wy);
    float t = xb - dl * (1.0f / 128.0f);
    int x0i, x1i; float wx;
    gs_coord(t, 64.0f, 127.0f, &x0i, &x1i, &wx);
    auto innerv = [&](int y, int x) -> float {
      float xbx = (x == 127) ? 1.0f : x * stepx;
      float drv = tr[(4 * y) * 512 + 4 * x] * 0.25f;
      float ti = xbx + drv * (1.0f / 128.0f);
      float g = 2.0f * ti - 1.0f;
      float ix2 = fminf(fmaxf((g + 1.0f) * 64.0f - 0.5f, 0.0f), 127.0f);
      float x0f = floorf(ix2);
      float wxp = ix2 - x0f;
      float x1f = fminf(x0f + 1.0f, 127.0f);
      return x0f * (1.0f - wxp) + x1f * wxp;
    };
    float v00 = innerv(y0i, x0i), v01 = innerv(y0i, x1i);
    float v10 = innerv(y1i, x0i), v11 = innerv(y1i, x1i);
    float l2r2l = v00 * (1.0f - wx) * (1.0f - wy) + v01 * wx * (1.0f - wy)
                + v10 * (1.0f - wx) * wy + v11 * wx * wy;
    bool masko = fabsf((float)j - l2r2l) < 3.0f;
    bool mk = masko && (dl > 0.0f) && (t >= 0.0f);
    maskArr[p] = mk ? 1.0f : 0.0f;
    xr[p] = t * 128.0f;   // exact: t*2^7
  }
}

// ========== k_compact: single block ballot + prefix scan (ascending) ==========
__global__ __launch_bounds__(256) void k_compact(const float* __restrict__ maskArr,
                                                 int* __restrict__ count,
                                                 int* __restrict__ list) {
  __shared__ int wsum[4];
  int tid = threadIdx.x;
  int lane = tid & 63, wave = tid >> 6;
  int base_p = tid * 64;
  unsigned long long bits = 0ull;
  const float4* m4 = (const float4*)(maskArr + base_p);
#pragma unroll
  for (int k = 0; k < 16; k++) {
    float4 v = m4[k];
    if (v.x > 0.0f) bits |= 1ull << (4 * k + 0);
    if (v.y > 0.0f) bits |= 1ull << (4 * k + 1);
    if (v.z > 0.0f) bits |= 1ull << (4 * k + 2);
    if (v.w > 0.0f) bits |= 1ull << (4 * k + 3);
  }
  int m = __popcll(bits);
  int scan = m;
#pragma unroll
  for (int off = 1; off < 64; off <<= 1) {
    int n = __shfl_up(scan, off, 64);
    if (lane >= off) scan += n;
  }
  if (lane == 63) wsum[wave] = scan;
  __syncthreads();
  int wbase = 0;
  for (int w = 0; w < wave; w++) wbase += wsum[w];
  int idx = wbase + scan - m;
  for (int k = 0; k < 64; k++) {
    if ((bits >> k) & 1ull) list[idx++] = base_p + k;
  }
  if (tid == 255) *count = idx;
}

// ============ k_B: colstats + prelude2 (slot-indexed, writes QTfc) ============
__global__ __launch_bounds__(256) void k_B(
    const _Float16* __restrict__ refTf, const _Float16* __restrict__ tgtTf,
    _Float16* __restrict__ QTfc, float* __restrict__ stats,
    const float* __restrict__ maskArr, const float* __restrict__ xr,
    float* __restrict__ S, float* __restrict__ logit0,
    const int* __restrict__ count, const int* __restrict__ list) {
  int blk = blockIdx.x;
  int tid = threadIdx.x;
  int lane = tid & 63;
  if (blk < 64) {
    // colstats: sub-wave per x
    int sub = tid >> 6;
    int xg = blk * 4 + sub;
    int b = xg >> 7, x = xg & 127;
    int xp = min(x + 1, 127);
    int c2 = lane * 2;
    int base = b * HWFM;
    f16_2 c0  = *(const f16_2*)(tgtTf + (size_t)(base + x) * CFM + c2);
    f16_2 c1  = *(const f16_2*)(tgtTf + (size_t)(base + WFM + x) * CFM + c2);
    f16_2 c0p = *(const f16_2*)(tgtTf + (size_t)(base + xp) * CFM + c2);
    f16_2 c1p = *(const f16_2*)(tgtTf + (size_t)(base + WFM + xp) * CFM + c2);
    float a0 = (float)c0[0], a1 = (float)c0[1];
    float b0 = (float)c1[0], b1 = (float)c1[1];
    float p0 = (float)c0p[0], p1 = (float)c0p[1];
    float q0 = (float)c1p[0], q1 = (float)c1p[1];
    float s[7];
    s[0] = a0 * a0 + a1 * a1;
    s[1] = a0 * b0 + a1 * b1;
    s[2] = b0 * b0 + b1 * b1;
    s[3] = a0 * p0 + a1 * p1;
    s[4] = a0 * q0 + a1 * q1;
    s[5] = b0 * p0 + b1 * p1;
    s[6] = b0 * q0 + b1 * q1;
#pragma unroll
    for (int o = 32; o; o >>= 1)
#pragma unroll
      for (int k = 0; k < 7; k++) s[k] += __shfl_xor(s[k], o, 64);
    if (lane == 0) {
      float* st = stats + (size_t)xg * 8;
#pragma unroll
      for (int k = 0; k < 7; k++) st[k] = s[k];
      st[7] = 0.0f;
    }
  } else {
    // prelude2: wave per compacted slot
    int wave = tid >> 6;
    int cnt = *count;
    int slot = (blk - 64) * 4 + wave;
    if (slot >= cnt) return;
    int p = list[slot];
    int b = p >> 13;
    int rem = p & (HWFM - 1);
    int i = rem >> 7;
    const float stepy = 1.0f / 63.0f;
    float yb = (i == 63) ? 1.0f : i * stepy;
    float t = xr[p] * (1.0f / 128.0f);   // exact recovery
    int y0i, y1i; float wy;
    gs_coord(yb, 32.0f, 63.0f, &y0i, &y1i, &wy);
    int x0i, x1i; float wx;
    gs_coord(t, 64.0f, 127.0f, &x0i, &x1i, &wx);

    int c2 = lane * 2;
    f16_2 q2 = *(const f16_2*)(refTf + (size_t)p * CFM + c2);
    int bo = b * HWFM;
    f16_2 a2 = *(const f16_2*)(tgtTf + (size_t)(bo + y0i * WFM + x0i) * CFM + c2);
    f16_2 b2 = *(const f16_2*)(tgtTf + (size_t)(bo + y0i * WFM + x1i) * CFM + c2);
    f16_2 cc2 = *(const f16_2*)(tgtTf + (size_t)(bo + y1i * WFM + x0i) * CFM + c2);
    f16_2 d2 = *(const f16_2*)(tgtTf + (size_t)(bo + y1i * WFM + x1i) * CFM + c2);

    float w00 = (1.0f - wx) * (1.0f - wy), w01 = wx * (1.0f - wy);
    float w10 = (1.0f - wx) * wy,          w11 = wx * wy;
    float q0 = (float)q2[0], q1 = (float)q2[1];
    float v0 = w00 * (float)a2[0] + w01 * (float)b2[0] + w10 * (float)cc2[0] + w11 * (float)d2[0];
    float v1 = w00 * (float)a2[1] + w01 * (float)b2[1] + w10 * (float)cc2[1] + w11 * (float)d2[1];

    float s0 = q0 * q0 + q1 * q1;
    float s1 = q0 * v0 + q1 * v1;
    float s2 = v0 * v0 + v1 * v1;
#pragma unroll
    for (int o = 32; o; o >>= 1) {
      s0 += __shfl_xor(s0, o, 64);
      s1 += __shfl_xor(s1, o, 64);
      s2 += __shfl_xor(s2, o, 64);
    }
    float inv = 1.0f / fmaxf(sqrtf(s0), 1e-12f);
    f16_2 qw; qw[0] = (_Float16)(q0 * inv); qw[1] = (_Float16)(q1 * inv);
    *(f16_2*)(QTfc + (size_t)slot * CFM + c2) = qw;   // compacted row
    if (lane == 0) {
      float lpos = (s1 * inv) / fmaxf(sqrtf(s2), 1e-12f);
      float lg0 = lpos / 0.07f;
      logit0[p] = lg0;
      S[p] = expf(lg0 - MSHIFT);
    }
  }
}

// ======== k_gemm_tiled: 128x128 LDS-staged MFMA GEMM + fused D + exp2 ========
// grid (48, 128). Block: 4 waves, each a 64x64 sub-tile. K=128 single shot.
// x-blocks 0..3 additionally compute one 128-col D chunk (tgt rows) first.
__global__ __launch_bounds__(256) void k_gemm_tiled(
    const _Float16* __restrict__ QTfc,    // [cnt][128] compacted queries
    const _Float16* __restrict__ queueTf, // [6144][128]
    const _Float16* __restrict__ tgtTf,   // [NPIX][128]
    const float2* __restrict__ qeb,       // [6144]
    float* __restrict__ S, float* __restrict__ D,
    const int* __restrict__ count, const int* __restrict__ list) {
  __shared__ _Float16 Bs[128 * BSTRIDE];   // 34816 B
  __shared__ float Srow[128];
  __shared__ int pb[128];
  int tid = threadIdx.x;
  int cnt = *count;
  int pblk = blockIdx.y * 128;
  if (pblk >= cnt) return;
  int wave = tid >> 6, lane = tid & 63;
  int quad = lane >> 4, l16 = lane & 15;
  int wm = wave >> 1, wn = wave & 1;

  if (tid < 128) {
    Srow[tid] = 0.0f;
    pb[tid] = list[min(pblk + tid, cnt - 1)] >> 13;
  }

  // A fragments from compacted rows (registers; rows >= cnt harmless garbage)
  f16_8 Af[4][4];
  int r0 = pblk + wm * 64;
#pragma unroll
  for (int mt = 0; mt < 4; mt++) {
    const _Float16* arow = QTfc + (size_t)(r0 + mt * 16 + l16) * CFM + quad * 8;
#pragma unroll
    for (int ks = 0; ks < 4; ks++)
      Af[mt][ks] = *(const f16_8*)(arow + ks * 32);
  }

  // ---- fused D chunk (x-blocks 0..3): B = 128 tgt rows ----
  if (blockIdx.x < 4) {
    int batch = blockIdx.x >> 1;
    const _Float16* bsrc = tgtTf + ((size_t)batch * HWFM + (blockIdx.x & 1) * 128) * CFM;
#pragma unroll
    for (int it = 0; it < 8; it++) {
      int idx = it * 256 + tid;
      int row = idx >> 4, c16 = idx & 15;
      f16_8 v = *(const f16_8*)(bsrc + (size_t)row * CFM + c16 * 8);
      *(f16_8*)(&Bs[row * BSTRIDE + c16 * 8]) = v;
    }
    __syncthreads();

    f32_4 acc[4][4];
#pragma unroll
    for (int mt = 0; mt < 4; mt++)
#pragma unroll
      for (int nt = 0; nt < 4; nt++)
        acc[mt][nt] = (f32_4){0.0f, 0.0f, 0.0f, 0.0f};
#pragma unroll
    for (int ks = 0; ks < 4; ks++) {
      f16_8 Bk[4];
#pragma unroll
      for (int nt = 0; nt < 4; nt++)
        Bk[nt] = *(const f16_8*)(&Bs[(wn * 64 + nt * 16 + l16) * BSTRIDE + ks * 32 + quad * 8]);
#pragma unroll
      for (int mt = 0; mt < 4; mt++)
#pragma unroll
        for (int nt = 0; nt < 4; nt++)
          acc[mt][nt] = __builtin_amdgcn_mfma_f32_16x16x32_f16(Af[mt][ks], Bk[nt], acc[mt][nt], 0, 0, 0);
    }
#pragma unroll
    for (int mt = 0; mt < 4; mt++)
#pragma unroll
      for (int nt = 0; nt < 4; nt++)
#pragma unroll
        for (int r = 0; r < 4; r++) {
          int rowloc = wm * 64 + mt * 16 + quad * 4 + r;
          int slot = pblk + rowloc;
          int colL = (blockIdx.x & 1) * 128 + wn * 64 + nt * 16 + l16;
          if (slot < cnt && pb[rowloc] == batch)
            D[(size_t)slot * 256 + colL] = acc[mt][nt][r];
        }
    __syncthreads();   // Bs free for re-stage
  }

  // ---- l_q chunk: B = 128 queue rows ----
  int n0 = blockIdx.x * 128;
  {
    const _Float16* bsrc = queueTf + (size_t)n0 * CFM;
#pragma unroll
    for (int it = 0; it < 8; it++) {
      int idx = it * 256 + tid;
      int row = idx >> 4, c16 = idx & 15;
      f16_8 v = *(const f16_8*)(bsrc + (size_t)row * CFM + c16 * 8);
      *(f16_8*)(&Bs[row * BSTRIDE + c16 * 8]) = v;
    }
  }
  float2 qb[4];
#pragma unroll
  for (int nt = 0; nt < 4; nt++) qb[nt] = qeb[n0 + wn * 64 + nt * 16 + l16];
  __syncthreads();

  f32_4 acc[4][4];
#pragma unroll
  for (int mt = 0; mt < 4; mt++)
#pragma unroll
    for (int nt = 0; nt < 4; nt++)
      acc[mt][nt] = (f32_4){0.0f, 0.0f, 0.0f, 0.0f};
#pragma unroll
  for (int ks = 0; ks < 4; ks++) {
    f16_8 Bk[4];
#pragma unroll
    for (int nt = 0; nt < 4; nt++)
      Bk[nt] = *(const f16_8*)(&Bs[(wn * 64 + nt * 16 + l16) * BSTRIDE + ks * 32 + quad * 8]);
#pragma unroll
    for (int mt = 0; mt < 4; mt++)
#pragma unroll
      for (int nt = 0; nt < 4; nt++)
        acc[mt][nt] = __builtin_amdgcn_mfma_f32_16x16x32_f16(Af[mt][ks], Bk[nt], acc[mt][nt], 0, 0, 0);
  }

  float rowsum[4][4];
#pragma unroll
  for (int mt = 0; mt < 4; mt++)
#pragma unroll
    for (int r = 0; r < 4; r++) rowsum[mt][r] = 0.0f;
#pragma unroll
  for (int nt = 0; nt < 4; nt++)
#pragma unroll
    for (int mt = 0; mt < 4; mt++)
#pragma unroll
      for (int r = 0; r < 4; r++)
        rowsum[mt][r] += exp2f(fmaf(acc[mt][nt][r], qb[nt].x, qb[nt].y));

#pragma unroll
  for (int mt = 0; mt < 4; mt++)
#pragma unroll
    for (int r = 0; r < 4; r++) {
      float vv = rowsum[mt][r];
      vv += __shfl_xor(vv, 1);
      vv += __shfl_xor(vv, 2);
      vv += __shfl_xor(vv, 4);
      vv += __shfl_xor(vv, 8);
      rowsum[mt][r] = vv;
    }
  if (l16 == 0) {
#pragma unroll
    for (int mt = 0; mt < 4; mt++)
#pragma unroll
      for (int r = 0; r < 4; r++)
        atomicAdd(&Srow[wm * 64 + mt * 16 + quad * 4 + r], rowsum[mt][r]);
  }
  __syncthreads();
  if (tid < 128) {
    int pr = pblk + tid;
    if (pr < cnt) atomicAdd(&S[list[pr]], Srow[tid]);
  }
}

// -------- negatives: wave-per-pixel, scalar via D + stats decomposition ----
__global__ __launch_bounds__(256) void k_negatives_lite(
    const float* __restrict__ D, const float* __restrict__ stats,
    const float* __restrict__ xr, float* __restrict__ S,
    const int* __restrict__ count, const int* __restrict__ list,
    uint32_t k1a, uint32_t k1b, uint32_t k2a, uint32_t k2b) {
  int tid = threadIdx.x;
  int wave = tid >> 6, lane = tid & 63;
  int cnt = *count;
  int slot = blockIdx.x * 4 + wave;
  if (slot >= cnt) return;
  int p = list[slot];
  int b = p >> 13;
  float esum = 0.0f;
  if (lane < NNEG) {
    uint32_t e = (uint32_t)(p * NNEG + lane);
    uint32_t h0, h1;
    threefry2x32(k1a, k1b, e, e + (uint32_t)NE, &h0, &h1);
    uint32_t off = ((h0 % 24u) * 16u + (h1 % 24u)) % 24u;
    float mag = (float)(1u + off);
    uint32_t ub;
    {
      uint32_t a, bm;
      if (e < EHALF_U) { threefry2x32(k2a, k2b, e, e + EHALF_U, &a, &bm); ub = a; }
      else             { threefry2x32(k2a, k2b, e - EHALF_U, e, &a, &bm); ub = bm; }
    }
    float u = __uint_as_float((ub >> 9) | 0x3F800000u) - 1.0f;
    float sg = (u > 0.5f) ? 1.0f : ((u < 0.5f) ? -1.0f : 0.0f);

    float v = xr[p] + mag * sg;
    float r = fmodf(v, 128.0f);
    if (r < 0.0f) r += 128.0f;
    float fx = r * (1.0f / 128.0f);
    float fy = fx * (1.0f / 64.0f);
    int x0i, x1i, y0i, y1i; float wx, wy;
    gs_coord(fx, 64.0f, 127.0f, &x0i, &x1i, &wx);
    gs_coord(fy, 32.0f, 63.0f, &y0i, &y1i, &wy);

    const float* Dp = D + (size_t)slot * 256;
    float d00 = Dp[x0i], d01 = Dp[x1i];
    float d10 = Dp[128 + x0i], d11 = Dp[128 + x1i];
    float u0 = 1.0f - wy, u1 = wy;
    float dv0 = u0 * d00 + u1 * d10;
    float dv1 = u0 * d01 + u1 * d11;
    float dot = (1.0f - wx) * dv0 + wx * dv1;

    const float* st0 = stats + (size_t)(b * 128 + x0i) * 8;
    const float* st1 = stats + (size_t)(b * 128 + x1i) * 8;
    float4 sa = *(const float4*)st0;
    float4 sb = *(const float4*)(st0 + 4);
    float4 sc = *(const float4*)st1;
    float a0 = u0 * u0, a1 = u0 * u1, a2 = u1 * u1;
    float nB0 = a0 * sa.x + 2.0f * a1 * sa.y + a2 * sa.z;
    float nB1 = a0 * sc.x + 2.0f * a1 * sc.y + a2 * sc.z;
    float cB  = a0 * sa.w + a1 * (sb.x + sb.y) + a2 * sb.z;
    float wx0 = 1.0f - wx;
    float nsq = wx0 * wx0 * nB0 + 2.0f * wx * wx0 * cB + wx * wx * nB1;
    float ln = dot / fmaxf(sqrtf(fmaxf(nsq, 0.0f)), 1e-12f);
    esum = __expf(ln * (1.0f / 0.07f) - MSHIFT);
  }
#pragma unroll
  for (int o = 32; o; o >>= 1) esum += __shfl_xor(esum, o, 64);
  if (lane == 0) atomicAdd(&S[p], esum);
}

__global__ __launch_bounds__(1024) void k_finalize(
    const float* __restrict__ S, const float* __restrict__ logit0,
    const float* __restrict__ maskArr, float* __restrict__ out) {
  int tid = threadIdx.x;
  const float cmask = logf(6061.0f);
  double acc = 0.0;
  for (int p = tid; p < NPIX; p += 1024) {
    float term = (maskArr[p] > 0.0f) ? (logf(S[p]) + MSHIFT - logit0[p]) : cmask;
    acc += (double)term;
  }
#pragma unroll
  for (int off = 32; off; off >>= 1) acc += __shfl_down(acc, off, 64);
  __shared__ double sd[16];
  if ((tid & 63) == 0) sd[tid >> 6] = acc;
  __syncthreads();
  if (tid == 0) {
    double tot = 0.0;
    for (int w = 0; w < 16; w++) tot += sd[w];
    out[0] = (float)(tot / (double)NPIX);
  }
}

extern "C" void kernel_launch(void* const* d_in, const int* in_sizes, int n_in,
                              void* d_out, int out_size, void* d_ws, size_t ws_size,
                              hipStream_t stream) {
  const float* ref   = (const float*)d_in[0];
  const float* tgt   = (const float*)d_in[1];
  const float* tl    = (const float*)d_in[2];
  const float* tr    = (const float*)d_in[3];
  const float* queue = (const float*)d_in[4];
  float* out = (float*)d_out;
  float* ws = (float*)d_ws;

  float2* qeb = (float2*)ws;                 // 6144 float2 -> 12288 floats
  float* S    = ws + 12288;                  // 16384
  float* lg0  = ws + 28672;                  // 16384
  float* mk   = ws + 45056;                  // 16384
  float* xr   = ws + 61440;                  // 16384 -> 77824
  int* count  = (int*)(ws + 77824);          // 1
  int* list   = (int*)(ws + 77840);          // 16384 -> 94224
  _Float16* QTfc    = (_Float16*)(ws + 94464);    // NPIX*128 f16 (compacted rows)
  _Float16* queueTf = (_Float16*)(ws + 1143040);  // 6144*128 f16
  _Float16* tgtTf   = (_Float16*)(ws + 1536256);  // NPIX*128 f16
  _Float16* refTf   = (_Float16*)(ws + 2584832);  // NPIX*128 f16
  float* stats = ws + 3633408;                    // 2048
  float* D     = ws + 3635456;                    // NPIX*256 f32

  // JAX: k1, k2 = split(key(1234))
  uint32_t b0o0, b0o1, b1o0, b1o1;
  threefry2x32(0u, 1234u, 0u, 2u, &b0o0, &b0o1);
  threefry2x32(0u, 1234u, 1u, 3u, &b1o0, &b1o1);
  uint32_t k1a = b0o0, k1b = b1o0, k2a = b0o1, k2b = b1o1;

  k_A<<<dim3(4952), dim3(256), 0, stream>>>(ref, tgt, queue, tl, tr,
                                            refTf, tgtTf, queueTf, qeb, mk, xr);
  k_compact<<<dim3(1), dim3(256), 0, stream>>>(mk, count, list);
  k_B<<<dim3(64 + 4096), dim3(256), 0, stream>>>(refTf, tgtTf, QTfc, stats,
                                                 mk, xr, S, lg0, count, list);
  k_gemm_tiled<<<dim3(48, 128), dim3(256), 0, stream>>>(QTfc, queueTf, tgtTf, qeb,
                                                        S, D, count, list);
  k_negatives_lite<<<dim3(NPIX / 4), dim3(256), 0, stream>>>(D, stats, xr, S, count, list,
                                                             k1a, k1b, k2a, k2b);
  k_finalize<<<dim3(1), dim3(1024), 0, stream>>>(S, lg0, mk, out);
}

// Round 13
// 137.402 us; speedup vs baseline: 1.2092x; 1.0895x over previous
//
#include <hip/hip_runtime.h>
#include <stdint.h>
#include <math.h>

#define HFM 64
#define WFM 128
#define CFM 128
#define BN 2
#define HWFM (HFM*WFM)          // 8192
#define NPIX (BN*HWFM)          // 16384
#define KQ 6000
#define KQP 6144                // padded to 48*128 (rows 6000..6143 zero)
#define NNEG 60
#define NE (NPIX*NNEG)          // 983040
#define EHALF_U 491520u
#define MSHIFT 15.0f
#define LOG2E 1.4426950408889634f
#define BSTRIDE 136             // LDS row stride in f16 (272 B)

typedef _Float16 f16_8 __attribute__((ext_vector_type(8)));
typedef _Float16 f16_2 __attribute__((ext_vector_type(2)));
typedef float f32_4 __attribute__((ext_vector_type(4)));

// ---------------- JAX threefry2x32 (bit-exact) ----------------
__host__ __device__ __forceinline__ void threefry2x32(uint32_t k0, uint32_t k1,
                                                      uint32_t x0, uint32_t x1,
                                                      uint32_t* o0, uint32_t* o1) {
  uint32_t ks2 = k0 ^ k1 ^ 0x1BD11BDAu;
  x0 += k0; x1 += k1;
#define TFR(r) { x0 += x1; x1 = (x1 << (r)) | (x1 >> (32 - (r))); x1 ^= x0; }
  TFR(13) TFR(15) TFR(26) TFR(6)
  x0 += k1;  x1 += ks2 + 1u;
  TFR(17) TFR(29) TFR(16) TFR(24)
  x0 += ks2; x1 += k0 + 2u;
  TFR(13) TFR(15) TFR(26) TFR(6)
  x0 += k0;  x1 += k1 + 3u;
  TFR(17) TFR(29) TFR(16) TFR(24)
  x0 += k1;  x1 += ks2 + 4u;
  TFR(13) TFR(15) TFR(26) TFR(6)
  x0 += ks2; x1 += k0 + 5u;
#undef TFR
  *o0 = x0; *o1 = x1;
}

// grid_sample coordinate helper (reference op order)
__device__ __forceinline__ void gs_coord(float t, float halfdim, float maxc,
                                         int* i0, int* i1, float* w) {
  float g = 2.0f * t - 1.0f;
  float x = (g + 1.0f) * halfdim - 0.5f;
  x = fminf(fmaxf(x, 0.0f), maxc);
  float f = floorf(x);
  *i0 = (int)f;
  *w = x - f;
  *i1 = (int)fminf(f + 1.0f, maxc);
}

// ================= k_A: transpose + qtrans + qprep + mask =================
__global__ __launch_bounds__(256) void k_A(
    const float* __restrict__ ref, const float* __restrict__ tgt,
    const float* __restrict__ queue,
    const float* __restrict__ target_l, const float* __restrict__ target_r,
    _Float16* __restrict__ refTf, _Float16* __restrict__ tgtTf,
    _Float16* __restrict__ queueTf, float2* __restrict__ qeb,
    float* __restrict__ maskArr, float* __restrict__ xr) {
  __shared__ float tile[32][33];
  int blk = blockIdx.x;
  int tid = threadIdx.x;
  if (blk < 4096) {
    int z = blk >> 10, yb_ = (blk >> 8) & 3, xb_ = blk & 255;
    int arr = z >> 1, b = z & 1;
    const float* src = (arr == 0 ? ref : tgt) + (size_t)b * CFM * HWFM;
    _Float16* dst = (arr == 0 ? refTf : tgtTf) + (size_t)b * HWFM * CFM;
    int x0 = xb_ * 32, y0 = yb_ * 32;
    int tx = tid & 31, ty = tid >> 5;
#pragma unroll
    for (int i = 0; i < 32; i += 8)
      tile[ty + i][tx] = src[(size_t)(y0 + ty + i) * HWFM + x0 + tx];
    __syncthreads();
#pragma unroll
    for (int i = 0; i < 32; i += 8)
      dst[(size_t)(x0 + ty + i) * CFM + (y0 + tx)] = (_Float16)tile[tx][ty + i];
  } else if (blk < 4864) {
    int q = blk - 4096;
    int cy = q / 192, nx = q - cy * 192;
    int n0 = nx * 32, c0 = cy * 32;
    int tx = tid & 31, ty = tid >> 5;
#pragma unroll
    for (int i = 0; i < 32; i += 8) {
      int n = n0 + tx;
      tile[ty + i][tx] = (n < KQ) ? queue[(size_t)(c0 + ty + i) * KQ + n] : 0.0f;
    }
    __syncthreads();
#pragma unroll
    for (int i = 0; i < 32; i += 8)
      queueTf[(size_t)(n0 + ty + i) * CFM + (c0 + tx)] = (_Float16)tile[tx][ty + i];
  } else if (blk < 4888) {
    int k = (blk - 4864) * 256 + tid;
    if (k < KQP) {
      if (k >= KQ) { qeb[k] = make_float2(0.0f, -1000.0f); }
      else {
        float ss = 0.0f;
        for (int c = 0; c < CFM; c++) { float v = queue[c * KQ + k]; ss += v * v; }
        float qi = 1.0f / fmaxf(sqrtf(ss), 1e-12f);
        qeb[k] = make_float2(qi * (LOG2E / 0.07f), -MSHIFT * LOG2E);
      }
    }
  } else {
    // mask: one thread per pixel
    int p = (blk - 4888) * 256 + tid;
    int b = p >> 13;
    int rem = p & (HWFM - 1);
    int i = rem >> 7, j = rem & 127;
    const float stepx = 1.0f / 127.0f, stepy = 1.0f / 63.0f;
    float xb = (j == 127) ? 1.0f : j * stepx;
    float yb = (i == 63) ? 1.0f : i * stepy;
    const float* tl = target_l + (size_t)b * 256 * 512;
    const float* tr = target_r + (size_t)b * 256 * 512;
    float dl = tl[(4 * i) * 512 + 4 * j] * 0.25f;
    int y0i, y1i; float wy;
    gs_coord(yb, 32.0f, 63.0f, &y0i, &y1i, &wy);
    float t = xb - dl * (1.0f / 128.0f);
    int x0i, x1i; float wx;
    gs_coord(t, 64.0f, 127.0f, &x0i, &x1i, &wx);
    auto innerv = [&](int y, int x) -> float {
      float xbx = (x == 127) ? 1.0f : x * stepx;
      float drv = tr[(4 * y) * 512 + 4 * x] * 0.25f;
      float ti = xbx + drv * (1.0f / 128.0f);
      float g = 2.0f * ti - 1.0f;
      float ix2 = fminf(fmaxf((g + 1.0f) * 64.0f - 0.5f, 0.0f), 127.0f);
      float x0f = floorf(ix2);
      float wxp = ix2 - x0f;
      float x1f = fminf(x0f + 1.0f, 127.0f);
      return x0f * (1.0f - wxp) + x1f * wxp;
    };
    float v00 = innerv(y0i, x0i), v01 = innerv(y0i, x1i);
    float v10 = innerv(y1i, x0i), v11 = innerv(y1i, x1i);
    float l2r2l = v00 * (1.0f - wx) * (1.0f - wy) + v01 * wx * (1.0f - wy)
                + v10 * (1.0f - wx) * wy + v11 * wx * wy;
    bool masko = fabsf((float)j - l2r2l) < 3.0f;
    bool mk = masko && (dl > 0.0f) && (t >= 0.0f);
    maskArr[p] = mk ? 1.0f : 0.0f;
    xr[p] = t * 128.0f;   // exact: t*2^7
  }
}

// ========== k_compact: single block ballot + prefix scan (ascending) ==========
__global__ __launch_bounds__(256) void k_compact(const float* __restrict__ maskArr,
                                                 int* __restrict__ count,
                                                 int* __restrict__ list) {
  __shared__ int wsum[4];
  int tid = threadIdx.x;
  int lane = tid & 63, wave = tid >> 6;
  int base_p = tid * 64;
  unsigned long long bits = 0ull;
  const float4* m4 = (const float4*)(maskArr + base_p);
#pragma unroll
  for (int k = 0; k < 16; k++) {
    float4 v = m4[k];
    if (v.x > 0.0f) bits |= 1ull << (4 * k + 0);
    if (v.y > 0.0f) bits |= 1ull << (4 * k + 1);
    if (v.z > 0.0f) bits |= 1ull << (4 * k + 2);
    if (v.w > 0.0f) bits |= 1ull << (4 * k + 3);
  }
  int m = __popcll(bits);
  int scan = m;
#pragma unroll
  for (int off = 1; off < 64; off <<= 1) {
    int n = __shfl_up(scan, off, 64);
    if (lane >= off) scan += n;
  }
  if (lane == 63) wsum[wave] = scan;
  __syncthreads();
  int wbase = 0;
  for (int w = 0; w < wave; w++) wbase += wsum[w];
  int idx = wbase + scan - m;
  for (int k = 0; k < 64; k++) {
    if ((bits >> k) & 1ull) list[idx++] = base_p + k;
  }
  if (tid == 255) *count = idx;
}

// ============ k_B: colstats + prelude2 (slot-indexed, writes QTfc) ============
__global__ __launch_bounds__(256) void k_B(
    const _Float16* __restrict__ refTf, const _Float16* __restrict__ tgtTf,
    _Float16* __restrict__ QTfc, float* __restrict__ stats,
    const float* __restrict__ maskArr, const float* __restrict__ xr,
    float* __restrict__ S, float* __restrict__ logit0,
    const int* __restrict__ count, const int* __restrict__ list) {
  int blk = blockIdx.x;
  int tid = threadIdx.x;
  int lane = tid & 63;
  if (blk < 64) {
    int sub = tid >> 6;
    int xg = blk * 4 + sub;
    int b = xg >> 7, x = xg & 127;
    int xp = min(x + 1, 127);
    int c2 = lane * 2;
    int base = b * HWFM;
    f16_2 c0  = *(const f16_2*)(tgtTf + (size_t)(base + x) * CFM + c2);
    f16_2 c1  = *(const f16_2*)(tgtTf + (size_t)(base + WFM + x) * CFM + c2);
    f16_2 c0p = *(const f16_2*)(tgtTf + (size_t)(base + xp) * CFM + c2);
    f16_2 c1p = *(const f16_2*)(tgtTf + (size_t)(base + WFM + xp) * CFM + c2);
    float a0 = (float)c0[0], a1 = (float)c0[1];
    float b0 = (float)c1[0], b1 = (float)c1[1];
    float p0 = (float)c0p[0], p1 = (float)c0p[1];
    float q0 = (float)c1p[0], q1 = (float)c1p[1];
    float s[7];
    s[0] = a0 * a0 + a1 * a1;
    s[1] = a0 * b0 + a1 * b1;
    s[2] = b0 * b0 + b1 * b1;
    s[3] = a0 * p0 + a1 * p1;
    s[4] = a0 * q0 + a1 * q1;
    s[5] = b0 * p0 + b1 * p1;
    s[6] = b0 * q0 + b1 * q1;
#pragma unroll
    for (int o = 32; o; o >>= 1)
#pragma unroll
      for (int k = 0; k < 7; k++) s[k] += __shfl_xor(s[k], o, 64);
    if (lane == 0) {
      float* st = stats + (size_t)xg * 8;
#pragma unroll
      for (int k = 0; k < 7; k++) st[k] = s[k];
      st[7] = 0.0f;
    }
  } else {
    int wave = tid >> 6;
    int cnt = *count;
    int slot = (blk - 64) * 4 + wave;
    if (slot >= cnt) return;
    int p = list[slot];
    int b = p >> 13;
    int rem = p & (HWFM - 1);
    int i = rem >> 7;
    const float stepy = 1.0f / 63.0f;
    float yb = (i == 63) ? 1.0f : i * stepy;
    float t = xr[p] * (1.0f / 128.0f);   // exact recovery
    int y0i, y1i; float wy;
    gs_coord(yb, 32.0f, 63.0f, &y0i, &y1i, &wy);
    int x0i, x1i; float wx;
    gs_coord(t, 64.0f, 127.0f, &x0i, &x1i, &wx);

    int c2 = lane * 2;
    f16_2 q2 = *(const f16_2*)(refTf + (size_t)p * CFM + c2);
    int bo = b * HWFM;
    f16_2 a2 = *(const f16_2*)(tgtTf + (size_t)(bo + y0i * WFM + x0i) * CFM + c2);
    f16_2 b2 = *(const f16_2*)(tgtTf + (size_t)(bo + y0i * WFM + x1i) * CFM + c2);
    f16_2 cc2 = *(const f16_2*)(tgtTf + (size_t)(bo + y1i * WFM + x0i) * CFM + c2);
    f16_2 d2 = *(const f16_2*)(tgtTf + (size_t)(bo + y1i * WFM + x1i) * CFM + c2);

    float w00 = (1.0f - wx) * (1.0f - wy), w01 = wx * (1.0f - wy);
    float w10 = (1.0f - wx) * wy,          w11 = wx * wy;
    float q0 = (float)q2[0], q1 = (float)q2[1];
    float v0 = w00 * (float)a2[0] + w01 * (float)b2[0] + w10 * (float)cc2[0] + w11 * (float)d2[0];
    float v1 = w00 * (float)a2[1] + w01 * (float)b2[1] + w10 * (float)cc2[1] + w11 * (float)d2[1];

    float s0 = q0 * q0 + q1 * q1;
    float s1 = q0 * v0 + q1 * v1;
    float s2 = v0 * v0 + v1 * v1;
#pragma unroll
    for (int o = 32; o; o >>= 1) {
      s0 += __shfl_xor(s0, o, 64);
      s1 += __shfl_xor(s1, o, 64);
      s2 += __shfl_xor(s2, o, 64);
    }
    float inv = 1.0f / fmaxf(sqrtf(s0), 1e-12f);
    f16_2 qw; qw[0] = (_Float16)(q0 * inv); qw[1] = (_Float16)(q1 * inv);
    *(f16_2*)(QTfc + (size_t)slot * CFM + c2) = qw;   // compacted row
    if (lane == 0) {
      float lpos = (s1 * inv) / fmaxf(sqrtf(s2), 1e-12f);
      float lg0 = lpos / 0.07f;
      logit0[p] = lg0;
      S[p] = expf(lg0 - MSHIFT);
    }
  }
}

// ======== k_gemm: 64-row tile, 4 LDS-staged chunks/block, fused D + exp2 ========
// grid (12, 256). Block = 4 waves (2x2), wave tile 32 rows x 64 cols.
// x-blocks 0..3 additionally compute one 128-col D chunk first.
__global__ __launch_bounds__(256) void k_gemm(
    const _Float16* __restrict__ QTfc,    // [cnt][128] compacted queries
    const _Float16* __restrict__ queueTf, // [6144][128]
    const _Float16* __restrict__ tgtTf,   // [NPIX][128]
    const float2* __restrict__ qeb,       // [6144]
    float* __restrict__ S, float* __restrict__ D,
    const int* __restrict__ count, const int* __restrict__ list) {
  __shared__ _Float16 Bs[128 * BSTRIDE];   // 34816 B
  __shared__ float Srow[64];
  __shared__ int pb[64];
  int tid = threadIdx.x;
  int cnt = *count;
  int pblk = blockIdx.y * 64;
  if (pblk >= cnt) return;
  int wave = tid >> 6, lane = tid & 63;
  int quad = lane >> 4, l16 = lane & 15;
  int wm = wave >> 1, wn = wave & 1;

  if (tid < 64) {
    Srow[tid] = 0.0f;
    pb[tid] = list[min(pblk + tid, cnt - 1)] >> 13;
  }

  // A fragments (clamped compacted rows)
  f16_8 Af[2][4];
  int r0 = pblk + wm * 32;
#pragma unroll
  for (int mt = 0; mt < 2; mt++) {
    const _Float16* arow = QTfc + (size_t)min(r0 + mt * 16 + l16, cnt - 1) * CFM + quad * 8;
#pragma unroll
    for (int ks = 0; ks < 4; ks++)
      Af[mt][ks] = *(const f16_8*)(arow + ks * 32);
  }

  // ---- fused D chunk (x-blocks 0..3) ----
  if (blockIdx.x < 4) {
    int batch = blockIdx.x >> 1;
    const _Float16* bsrc = tgtTf + ((size_t)batch * HWFM + (blockIdx.x & 1) * 128) * CFM;
#pragma unroll
    for (int it = 0; it < 8; it++) {
      int idx = it * 256 + tid;
      int row = idx >> 4, c16 = idx & 15;
      *(f16_8*)(&Bs[row * BSTRIDE + c16 * 8]) =
          *(const f16_8*)(bsrc + (size_t)row * CFM + c16 * 8);
    }
    __syncthreads();

    f32_4 acc[2][4];
#pragma unroll
    for (int mt = 0; mt < 2; mt++)
#pragma unroll
      for (int nt = 0; nt < 4; nt++)
        acc[mt][nt] = (f32_4){0.0f, 0.0f, 0.0f, 0.0f};
#pragma unroll
    for (int ks = 0; ks < 4; ks++) {
      f16_8 Bk[4];
#pragma unroll
      for (int nt = 0; nt < 4; nt++)
        Bk[nt] = *(const f16_8*)(&Bs[(wn * 64 + nt * 16 + l16) * BSTRIDE + ks * 32 + quad * 8]);
#pragma unroll
      for (int mt = 0; mt < 2; mt++)
#pragma unroll
        for (int nt = 0; nt < 4; nt++)
          acc[mt][nt] = __builtin_amdgcn_mfma_f32_16x16x32_f16(Af[mt][ks], Bk[nt], acc[mt][nt], 0, 0, 0);
    }
#pragma unroll
    for (int mt = 0; mt < 2; mt++)
#pragma unroll
      for (int nt = 0; nt < 4; nt++)
#pragma unroll
        for (int r = 0; r < 4; r++) {
          int rowloc = wm * 32 + mt * 16 + quad * 4 + r;
          int slot = pblk + rowloc;
          int colL = (blockIdx.x & 1) * 128 + wn * 64 + nt * 16 + l16;
          if (slot < cnt && pb[rowloc] == batch)
            D[(size_t)slot * 256 + colL] = acc[mt][nt][r];
        }
    __syncthreads();
  }

  // ---- l_q: 4 chunks of 128 cols ----
  float rowsum[2][4] = {{0.0f,0.0f,0.0f,0.0f},{0.0f,0.0f,0.0f,0.0f}};
#pragma unroll
  for (int ic = 0; ic < 4; ic++) {
    int n0 = (blockIdx.x * 4 + ic) * 128;
    {
      const _Float16* bsrc = queueTf + (size_t)n0 * CFM;
#pragma unroll
      for (int it = 0; it < 8; it++) {
        int idx = it * 256 + tid;
        int row = idx >> 4, c16 = idx & 15;
        *(f16_8*)(&Bs[row * BSTRIDE + c16 * 8]) =
            *(const f16_8*)(bsrc + (size_t)row * CFM + c16 * 8);
      }
    }
    float2 qb[4];
#pragma unroll
    for (int nt = 0; nt < 4; nt++) qb[nt] = qeb[n0 + wn * 64 + nt * 16 + l16];
    __syncthreads();

    f32_4 acc[2][4];
#pragma unroll
    for (int mt = 0; mt < 2; mt++)
#pragma unroll
      for (int nt = 0; nt < 4; nt++)
        acc[mt][nt] = (f32_4){0.0f, 0.0f, 0.0f, 0.0f};
#pragma unroll
    for (int ks = 0; ks < 4; ks++) {
      f16_8 Bk[4];
#pragma unroll
      for (int nt = 0; nt < 4; nt++)
        Bk[nt] = *(const f16_8*)(&Bs[(wn * 64 + nt * 16 + l16) * BSTRIDE + ks * 32 + quad * 8]);
#pragma unroll
      for (int mt = 0; mt < 2; mt++)
#pragma unroll
        for (int nt = 0; nt < 4; nt++)
          acc[mt][nt] = __builtin_amdgcn_mfma_f32_16x16x32_f16(Af[mt][ks], Bk[nt], acc[mt][nt], 0, 0, 0);
    }
#pragma unroll
    for (int nt = 0; nt < 4; nt++)
#pragma unroll
      for (int mt = 0; mt < 2; mt++)
#pragma unroll
        for (int r = 0; r < 4; r++)
          rowsum[mt][r] += exp2f(fmaf(acc[mt][nt][r], qb[nt].x, qb[nt].y));
    __syncthreads();   // Bs free for next stage
  }

#pragma unroll
  for (int mt = 0; mt < 2; mt++)
#pragma unroll
    for (int r = 0; r < 4; r++) {
      float vv = rowsum[mt][r];
      vv += __shfl_xor(vv, 1);
      vv += __shfl_xor(vv, 2);
      vv += __shfl_xor(vv, 4);
      vv += __shfl_xor(vv, 8);
      rowsum[mt][r] = vv;
    }
  if (l16 == 0) {
#pragma unroll
    for (int mt = 0; mt < 2; mt++)
#pragma unroll
      for (int r = 0; r < 4; r++)
        atomicAdd(&Srow[wm * 32 + mt * 16 + quad * 4 + r], rowsum[mt][r]);
  }
  __syncthreads();
  if (tid < 64) {
    int pr = pblk + tid;
    if (pr < cnt) atomicAdd(&S[list[pr]], Srow[tid]);
  }
}

// -------- negatives: wave-per-pixel, scalar via D + stats decomposition ----
__global__ __launch_bounds__(256) void k_negatives_lite(
    const float* __restrict__ D, const float* __restrict__ stats,
    const float* __restrict__ xr, float* __restrict__ S,
    const int* __restrict__ count, const int* __restrict__ list,
    uint32_t k1a, uint32_t k1b, uint32_t k2a, uint32_t k2b) {
  int tid = threadIdx.x;
  int wave = tid >> 6, lane = tid & 63;
  int cnt = *count;
  int slot = blockIdx.x * 4 + wave;
  if (slot >= cnt) return;
  int p = list[slot];
  int b = p >> 13;
  float esum = 0.0f;
  if (lane < NNEG) {
    uint32_t e = (uint32_t)(p * NNEG + lane);
    uint32_t h0, h1;
    threefry2x32(k1a, k1b, e, e + (uint32_t)NE, &h0, &h1);
    uint32_t off = ((h0 % 24u) * 16u + (h1 % 24u)) % 24u;
    float mag = (float)(1u + off);
    uint32_t ub;
    {
      uint32_t a, bm;
      if (e < EHALF_U) { threefry2x32(k2a, k2b, e, e + EHALF_U, &a, &bm); ub = a; }
      else             { threefry2x32(k2a, k2b, e - EHALF_U, e, &a, &bm); ub = bm; }
    }
    float u = __uint_as_float((ub >> 9) | 0x3F800000u) - 1.0f;
    float sg = (u > 0.5f) ? 1.0f : ((u < 0.5f) ? -1.0f : 0.0f);

    float v = xr[p] + mag * sg;
    float r = fmodf(v, 128.0f);
    if (r < 0.0f) r += 128.0f;
    float fx = r * (1.0f / 128.0f);
    float fy = fx * (1.0f / 64.0f);
    int x0i, x1i, y0i, y1i; float wx, wy;
    gs_coord(fx, 64.0f, 127.0f, &x0i, &x1i, &wx);
    gs_coord(fy, 32.0f, 63.0f, &y0i, &y1i, &wy);

    const float* Dp = D + (size_t)slot * 256;
    float d00 = Dp[x0i], d01 = Dp[x1i];
    float d10 = Dp[128 + x0i], d11 = Dp[128 + x1i];
    float u0 = 1.0f - wy, u1 = wy;
    float dv0 = u0 * d00 + u1 * d10;
    float dv1 = u0 * d01 + u1 * d11;
    float dot = (1.0f - wx) * dv0 + wx * dv1;

    const float* st0 = stats + (size_t)(b * 128 + x0i) * 8;
    const float* st1 = stats + (size_t)(b * 128 + x1i) * 8;
    float4 sa = *(const float4*)st0;
    float4 sb = *(const float4*)(st0 + 4);
    float4 sc = *(const float4*)st1;
    float a0 = u0 * u0, a1 = u0 * u1, a2 = u1 * u1;
    float nB0 = a0 * sa.x + 2.0f * a1 * sa.y + a2 * sa.z;
    float nB1 = a0 * sc.x + 2.0f * a1 * sc.y + a2 * sc.z;
    float cB  = a0 * sa.w + a1 * (sb.x + sb.y) + a2 * sb.z;
    float wx0 = 1.0f - wx;
    float nsq = wx0 * wx0 * nB0 + 2.0f * wx * wx0 * cB + wx * wx * nB1;
    float ln = dot / fmaxf(sqrtf(fmaxf(nsq, 0.0f)), 1e-12f);
    esum = __expf(ln * (1.0f / 0.07f) - MSHIFT);
  }
#pragma unroll
  for (int o = 32; o; o >>= 1) esum += __shfl_xor(esum, o, 64);
  if (lane == 0) atomicAdd(&S[p], esum);
}

__global__ __launch_bounds__(1024) void k_finalize(
    const float* __restrict__ S, const float* __restrict__ logit0,
    const float* __restrict__ maskArr, float* __restrict__ out) {
  int tid = threadIdx.x;
  const float cmask = logf(6061.0f);
  double acc = 0.0;
  for (int p = tid; p < NPIX; p += 1024) {
    float term = (maskArr[p] > 0.0f) ? (logf(S[p]) + MSHIFT - logit0[p]) : cmask;
    acc += (double)term;
  }
#pragma unroll
  for (int off = 32; off; off >>= 1) acc += __shfl_down(acc, off, 64);
  __shared__ double sd[16];
  if ((tid & 63) == 0) sd[tid >> 6] = acc;
  __syncthreads();
  if (tid == 0) {
    double tot = 0.0;
    for (int w = 0; w < 16; w++) tot += sd[w];
    out[0] = (float)(tot / (double)NPIX);
  }
}

extern "C" void kernel_launch(void* const* d_in, const int* in_sizes, int n_in,
                              void* d_out, int out_size, void* d_ws, size_t ws_size,
                              hipStream_t stream) {
  const float* ref   = (const float*)d_in[0];
  const float* tgt   = (const float*)d_in[1];
  const float* tl    = (const float*)d_in[2];
  const float* tr    = (const float*)d_in[3];
  const float* queue = (const float*)d_in[4];
  float* out = (float*)d_out;
  float* ws = (float*)d_ws;

  float2* qeb = (float2*)ws;                 // 6144 float2 -> 12288 floats
  float* S    = ws + 12288;                  // 16384
  float* lg0  = ws + 28672;                  // 16384
  float* mk   = ws + 45056;                  // 16384
  float* xr   = ws + 61440;                  // 16384 -> 77824
  int* count  = (int*)(ws + 77824);          // 1
  int* list   = (int*)(ws + 77840);          // 16384 -> 94224
  _Float16* QTfc    = (_Float16*)(ws + 94464);    // NPIX*128 f16 (compacted rows)
  _Float16* queueTf = (_Float16*)(ws + 1143040);  // 6144*128 f16
  _Float16* tgtTf   = (_Float16*)(ws + 1536256);  // NPIX*128 f16
  _Float16* refTf   = (_Float16*)(ws + 2584832);  // NPIX*128 f16
  float* stats = ws + 3633408;                    // 2048
  float* D     = ws + 3635456;                    // NPIX*256 f32

  // JAX: k1, k2 = split(key(1234))
  uint32_t b0o0, b0o1, b1o0, b1o1;
  threefry2x32(0u, 1234u, 0u, 2u, &b0o0, &b0o1);
  threefry2x32(0u, 1234u, 1u, 3u, &b1o0, &b1o1);
  uint32_t k1a = b0o0, k1b = b1o0, k2a = b0o1, k2b = b1o1;

  k_A<<<dim3(4952), dim3(256), 0, stream>>>(ref, tgt, queue, tl, tr,
                                            refTf, tgtTf, queueTf, qeb, mk, xr);
  k_compact<<<dim3(1), dim3(256), 0, stream>>>(mk, count, list);
  k_B<<<dim3(64 + 4096), dim3(256), 0, stream>>>(refTf, tgtTf, QTfc, stats,
                                                 mk, xr, S, lg0, count, list);
  k_gemm<<<dim3(12, NPIX / 64), dim3(256), 0, stream>>>(QTfc, queueTf, tgtTf, qeb,
                                                        S, D, count, list);
  k_negatives_lite<<<dim3(NPIX / 4), dim3(256), 0, stream>>>(D, stats, xr, S, count, list,
                                                             k1a, k1b, k2a, k2b);
  k_finalize<<<dim3(1), dim3(1024), 0, stream>>>(S, lg0, mk, out);
}

// Round 14
// 130.837 us; speedup vs baseline: 1.2698x; 1.0502x over previous
//
#include <hip/hip_runtime.h>
#include <stdint.h>
#include <math.h>

#define HFM 64
#define WFM 128
#define CFM 128
#define BN 2
#define HWFM (HFM*WFM)          // 8192
#define NPIX (BN*HWFM)          // 16384
#define KQ 6000
#define KQP 6144                // padded to 48*128 (rows 6000..6143 zero)
#define NNEG 60
#define NE (NPIX*NNEG)          // 983040
#define EHALF_U 491520u
#define MSHIFT 15.0f
#define LOG2E 1.4426950408889634f
#define BSTRIDE 136             // LDS row stride in f16 (272 B)

typedef _Float16 f16_8 __attribute__((ext_vector_type(8)));
typedef _Float16 f16_2 __attribute__((ext_vector_type(2)));
typedef float f32_4 __attribute__((ext_vector_type(4)));

// ---------------- JAX threefry2x32 (bit-exact) ----------------
__host__ __device__ __forceinline__ void threefry2x32(uint32_t k0, uint32_t k1,
                                                      uint32_t x0, uint32_t x1,
                                                      uint32_t* o0, uint32_t* o1) {
  uint32_t ks2 = k0 ^ k1 ^ 0x1BD11BDAu;
  x0 += k0; x1 += k1;
#define TFR(r) { x0 += x1; x1 = (x1 << (r)) | (x1 >> (32 - (r))); x1 ^= x0; }
  TFR(13) TFR(15) TFR(26) TFR(6)
  x0 += k1;  x1 += ks2 + 1u;
  TFR(17) TFR(29) TFR(16) TFR(24)
  x0 += ks2; x1 += k0 + 2u;
  TFR(13) TFR(15) TFR(26) TFR(6)
  x0 += k0;  x1 += k1 + 3u;
  TFR(17) TFR(29) TFR(16) TFR(24)
  x0 += k1;  x1 += ks2 + 4u;
  TFR(13) TFR(15) TFR(26) TFR(6)
  x0 += ks2; x1 += k0 + 5u;
#undef TFR
  *o0 = x0; *o1 = x1;
}

// grid_sample coordinate helper (reference op order)
__device__ __forceinline__ void gs_coord(float t, float halfdim, float maxc,
                                         int* i0, int* i1, float* w) {
  float g = 2.0f * t - 1.0f;
  float x = (g + 1.0f) * halfdim - 0.5f;
  x = fminf(fmaxf(x, 0.0f), maxc);
  float f = floorf(x);
  *i0 = (int)f;
  *w = x - f;
  *i1 = (int)fminf(f + 1.0f, maxc);
}

// ====== k_A: mask (first, latency-bound) + qprep + qtrans + transpose ======
// blocks [0,64): mask; [64,88): qeb prep; [88,856): queue transpose;
// [856,4952): feature transpose.
__global__ __launch_bounds__(256) void k_A(
    const float* __restrict__ ref, const float* __restrict__ tgt,
    const float* __restrict__ queue,
    const float* __restrict__ target_l, const float* __restrict__ target_r,
    _Float16* __restrict__ refTf, _Float16* __restrict__ tgtTf,
    _Float16* __restrict__ queueTf, float2* __restrict__ qeb,
    float* __restrict__ maskArr, float* __restrict__ xr) {
  __shared__ float tile[32][33];
  int blk = blockIdx.x;
  int tid = threadIdx.x;
  if (blk < 64) {
    // mask: one thread per pixel
    int p = blk * 256 + tid;
    int b = p >> 13;
    int rem = p & (HWFM - 1);
    int i = rem >> 7, j = rem & 127;
    const float stepx = 1.0f / 127.0f, stepy = 1.0f / 63.0f;
    float xb = (j == 127) ? 1.0f : j * stepx;
    float yb = (i == 63) ? 1.0f : i * stepy;
    const float* tl = target_l + (size_t)b * 256 * 512;
    const float* tr = target_r + (size_t)b * 256 * 512;
    float dl = tl[(4 * i) * 512 + 4 * j] * 0.25f;
    int y0i, y1i; float wy;
    gs_coord(yb, 32.0f, 63.0f, &y0i, &y1i, &wy);
    float t = xb - dl * (1.0f / 128.0f);
    int x0i, x1i; float wx;
    gs_coord(t, 64.0f, 127.0f, &x0i, &x1i, &wx);
    auto innerv = [&](int y, int x) -> float {
      float xbx = (x == 127) ? 1.0f : x * stepx;
      float drv = tr[(4 * y) * 512 + 4 * x] * 0.25f;
      float ti = xbx + drv * (1.0f / 128.0f);
      float g = 2.0f * ti - 1.0f;
      float ix2 = fminf(fmaxf((g + 1.0f) * 64.0f - 0.5f, 0.0f), 127.0f);
      float x0f = floorf(ix2);
      float wxp = ix2 - x0f;
      float x1f = fminf(x0f + 1.0f, 127.0f);
      return x0f * (1.0f - wxp) + x1f * wxp;
    };
    float v00 = innerv(y0i, x0i), v01 = innerv(y0i, x1i);
    float v10 = innerv(y1i, x0i), v11 = innerv(y1i, x1i);
    float l2r2l = v00 * (1.0f - wx) * (1.0f - wy) + v01 * wx * (1.0f - wy)
                + v10 * (1.0f - wx) * wy + v11 * wx * wy;
    bool masko = fabsf((float)j - l2r2l) < 3.0f;
    bool mk = masko && (dl > 0.0f) && (t >= 0.0f);
    maskArr[p] = mk ? 1.0f : 0.0f;
    xr[p] = t * 128.0f;   // exact: t*2^7
  } else if (blk < 88) {
    int k = (blk - 64) * 256 + tid;
    if (k < KQP) {
      if (k >= KQ) { qeb[k] = make_float2(0.0f, -1000.0f); }
      else {
        float ss = 0.0f;
        for (int c = 0; c < CFM; c++) { float v = queue[c * KQ + k]; ss += v * v; }
        float qi = 1.0f / fmaxf(sqrtf(ss), 1e-12f);
        qeb[k] = make_float2(qi * (LOG2E / 0.07f), -MSHIFT * LOG2E);
      }
    }
  } else if (blk < 856) {
    int q = blk - 88;
    int cy = q / 192, nx = q - cy * 192;
    int n0 = nx * 32, c0 = cy * 32;
    int tx = tid & 31, ty = tid >> 5;
#pragma unroll
    for (int i = 0; i < 32; i += 8) {
      int n = n0 + tx;
      tile[ty + i][tx] = (n < KQ) ? queue[(size_t)(c0 + ty + i) * KQ + n] : 0.0f;
    }
    __syncthreads();
#pragma unroll
    for (int i = 0; i < 32; i += 8)
      queueTf[(size_t)(n0 + ty + i) * CFM + (c0 + tx)] = (_Float16)tile[tx][ty + i];
  } else {
    int fblk = blk - 856;
    int z = fblk >> 10, yb_ = (fblk >> 8) & 3, xb_ = fblk & 255;
    int arr = z >> 1, b = z & 1;
    const float* src = (arr == 0 ? ref : tgt) + (size_t)b * CFM * HWFM;
    _Float16* dst = (arr == 0 ? refTf : tgtTf) + (size_t)b * HWFM * CFM;
    int x0 = xb_ * 32, y0 = yb_ * 32;
    int tx = tid & 31, ty = tid >> 5;
#pragma unroll
    for (int i = 0; i < 32; i += 8)
      tile[ty + i][tx] = src[(size_t)(y0 + ty + i) * HWFM + x0 + tx];
    __syncthreads();
#pragma unroll
    for (int i = 0; i < 32; i += 8)
      dst[(size_t)(x0 + ty + i) * CFM + (y0 + tx)] = (_Float16)tile[tx][ty + i];
  }
}

// ====== k_B: compact (block 0) + colstats (1..64) + prelude p-indexed ======
__global__ __launch_bounds__(256) void k_B(
    const _Float16* __restrict__ refTf, const _Float16* __restrict__ tgtTf,
    _Float16* __restrict__ QTf, float* __restrict__ stats,
    const float* __restrict__ maskArr, const float* __restrict__ xr,
    float* __restrict__ S, float* __restrict__ logit0,
    int* __restrict__ count, int* __restrict__ list) {
  __shared__ int wsum[4];
  int blk = blockIdx.x;
  int tid = threadIdx.x;
  int lane = tid & 63;
  if (blk == 0) {
    // compact: thread handles 64 consecutive pixels
    int wave = tid >> 6;
    int base_p = tid * 64;
    unsigned long long bits = 0ull;
    const float4* m4 = (const float4*)(maskArr + base_p);
#pragma unroll
    for (int k = 0; k < 16; k++) {
      float4 v = m4[k];
      if (v.x > 0.0f) bits |= 1ull << (4 * k + 0);
      if (v.y > 0.0f) bits |= 1ull << (4 * k + 1);
      if (v.z > 0.0f) bits |= 1ull << (4 * k + 2);
      if (v.w > 0.0f) bits |= 1ull << (4 * k + 3);
    }
    int m = __popcll(bits);
    int scan = m;
#pragma unroll
    for (int off = 1; off < 64; off <<= 1) {
      int n = __shfl_up(scan, off, 64);
      if (lane >= off) scan += n;
    }
    if (lane == 63) wsum[wave] = scan;
    __syncthreads();
    int wbase = 0;
    for (int w = 0; w < wave; w++) wbase += wsum[w];
    int idx = wbase + scan - m;
    for (int k = 0; k < 64; k++) {
      if ((bits >> k) & 1ull) list[idx++] = base_p + k;
    }
    if (tid == 255) *count = idx;
  } else if (blk < 65) {
    int sub = tid >> 6;
    int xg = (blk - 1) * 4 + sub;
    int b = xg >> 7, x = xg & 127;
    int xp = min(x + 1, 127);
    int c2 = lane * 2;
    int base = b * HWFM;
    f16_2 c0  = *(const f16_2*)(tgtTf + (size_t)(base + x) * CFM + c2);
    f16_2 c1  = *(const f16_2*)(tgtTf + (size_t)(base + WFM + x) * CFM + c2);
    f16_2 c0p = *(const f16_2*)(tgtTf + (size_t)(base + xp) * CFM + c2);
    f16_2 c1p = *(const f16_2*)(tgtTf + (size_t)(base + WFM + xp) * CFM + c2);
    float a0 = (float)c0[0], a1 = (float)c0[1];
    float b0 = (float)c1[0], b1 = (float)c1[1];
    float p0 = (float)c0p[0], p1 = (float)c0p[1];
    float q0 = (float)c1p[0], q1 = (float)c1p[1];
    float s[7];
    s[0] = a0 * a0 + a1 * a1;
    s[1] = a0 * b0 + a1 * b1;
    s[2] = b0 * b0 + b1 * b1;
    s[3] = a0 * p0 + a1 * p1;
    s[4] = a0 * q0 + a1 * q1;
    s[5] = b0 * p0 + b1 * p1;
    s[6] = b0 * q0 + b1 * q1;
#pragma unroll
    for (int o = 32; o; o >>= 1)
#pragma unroll
      for (int k = 0; k < 7; k++) s[k] += __shfl_xor(s[k], o, 64);
    if (lane == 0) {
      float* st = stats + (size_t)xg * 8;
#pragma unroll
      for (int k = 0; k < 7; k++) st[k] = s[k];
      st[7] = 0.0f;
    }
  } else {
    // prelude: wave per pixel p (p-indexed), early-exit masked
    int wave = tid >> 6;
    int p = (blk - 65) * 4 + wave;
    float mk = maskArr[p];
    if (mk == 0.0f) return;
    int b = p >> 13;
    int rem = p & (HWFM - 1);
    int i = rem >> 7;
    const float stepy = 1.0f / 63.0f;
    float yb = (i == 63) ? 1.0f : i * stepy;
    float t = xr[p] * (1.0f / 128.0f);   // exact recovery
    int y0i, y1i; float wy;
    gs_coord(yb, 32.0f, 63.0f, &y0i, &y1i, &wy);
    int x0i, x1i; float wx;
    gs_coord(t, 64.0f, 127.0f, &x0i, &x1i, &wx);

    int c2 = lane * 2;
    f16_2 q2 = *(const f16_2*)(refTf + (size_t)p * CFM + c2);
    int bo = b * HWFM;
    f16_2 a2 = *(const f16_2*)(tgtTf + (size_t)(bo + y0i * WFM + x0i) * CFM + c2);
    f16_2 b2 = *(const f16_2*)(tgtTf + (size_t)(bo + y0i * WFM + x1i) * CFM + c2);
    f16_2 cc2 = *(const f16_2*)(tgtTf + (size_t)(bo + y1i * WFM + x0i) * CFM + c2);
    f16_2 d2 = *(const f16_2*)(tgtTf + (size_t)(bo + y1i * WFM + x1i) * CFM + c2);

    float w00 = (1.0f - wx) * (1.0f - wy), w01 = wx * (1.0f - wy);
    float w10 = (1.0f - wx) * wy,          w11 = wx * wy;
    float q0 = (float)q2[0], q1 = (float)q2[1];
    float v0 = w00 * (float)a2[0] + w01 * (float)b2[0] + w10 * (float)cc2[0] + w11 * (float)d2[0];
    float v1 = w00 * (float)a2[1] + w01 * (float)b2[1] + w10 * (float)cc2[1] + w11 * (float)d2[1];

    float s0 = q0 * q0 + q1 * q1;
    float s1 = q0 * v0 + q1 * v1;
    float s2 = v0 * v0 + v1 * v1;
#pragma unroll
    for (int o = 32; o; o >>= 1) {
      s0 += __shfl_xor(s0, o, 64);
      s1 += __shfl_xor(s1, o, 64);
      s2 += __shfl_xor(s2, o, 64);
    }
    float inv = 1.0f / fmaxf(sqrtf(s0), 1e-12f);
    f16_2 qw; qw[0] = (_Float16)(q0 * inv); qw[1] = (_Float16)(q1 * inv);
    *(f16_2*)(QTf + (size_t)p * CFM + c2) = qw;
    if (lane == 0) {
      float lpos = (s1 * inv) / fmaxf(sqrtf(s2), 1e-12f);
      float lg0 = lpos / 0.07f;
      logit0[p] = lg0;
      S[p] = expf(lg0 - MSHIFT);
    }
  }
}

// ======== k_gemm: 64-row tile, 8 chunks/block, pipelined LDS double-buffer ====
// grid (6, 256). x-blocks 0..3 additionally compute one 128-col D chunk first.
// Pipeline: issue next chunk's global loads -> MFMA current chunk -> ds_write.
__global__ __launch_bounds__(256) void k_gemm(
    const _Float16* __restrict__ QTf,     // [NPIX][128] (p-indexed, unmasked rows valid)
    const _Float16* __restrict__ queueTf, // [6144][128]
    const _Float16* __restrict__ tgtTf,   // [NPIX][128]
    const float2* __restrict__ qeb,       // [6144]
    float* __restrict__ S, float* __restrict__ D,
    const int* __restrict__ count, const int* __restrict__ list) {
  __shared__ _Float16 Bs[2][128 * BSTRIDE];   // 2 x 34816 B
  __shared__ float Srow[64];
  __shared__ int pb[64];
  int tid = threadIdx.x;
  int cnt = *count;
  int pblk = blockIdx.y * 64;
  if (pblk >= cnt) return;
  int wave = tid >> 6, lane = tid & 63;
  int quad = lane >> 4, l16 = lane & 15;
  int wm = wave >> 1, wn = wave & 1;

  if (tid < 64) {
    Srow[tid] = 0.0f;
    pb[tid] = list[min(pblk + tid, cnt - 1)] >> 13;
  }

  // A fragments via list indirection
  f16_8 Af[2][4];
  int r0 = pblk + wm * 32;
#pragma unroll
  for (int mt = 0; mt < 2; mt++) {
    int prow = list[min(r0 + mt * 16 + l16, cnt - 1)];
    const _Float16* arow = QTf + (size_t)prow * CFM + quad * 8;
#pragma unroll
    for (int ks = 0; ks < 4; ks++)
      Af[mt][ks] = *(const f16_8*)(arow + ks * 32);
  }

  f16_8 sreg[8];
  int srow[8], sc16[8];
#pragma unroll
  for (int it = 0; it < 8; it++) {
    int idx = it * 256 + tid;
    srow[it] = idx >> 4; sc16[it] = idx & 15;
  }
  auto load_src = [&](const _Float16* bsrc) {
#pragma unroll
    for (int it = 0; it < 8; it++)
      sreg[it] = *(const f16_8*)(bsrc + (size_t)srow[it] * CFM + sc16[it] * 8);
  };
  auto write_lds = [&](int buf) {
#pragma unroll
    for (int it = 0; it < 8; it++)
      *(f16_8*)(&Bs[buf][srow[it] * BSTRIDE + sc16[it] * 8]) = sreg[it];
  };

  int nbase = blockIdx.x * 8 * 128;
  int cur;
  float rowsum[2][4] = {{0.0f,0.0f,0.0f,0.0f},{0.0f,0.0f,0.0f,0.0f}};

  if (blockIdx.x < 4) {
    // D chunk
    int batch = blockIdx.x >> 1;
    load_src(tgtTf + ((size_t)batch * HWFM + (blockIdx.x & 1) * 128) * CFM);
    write_lds(0);
    __syncthreads();
    // prefetch l_q chunk 0 while computing D
    load_src(queueTf + (size_t)nbase * CFM);
    f32_4 acc[2][4];
#pragma unroll
    for (int mt = 0; mt < 2; mt++)
#pragma unroll
      for (int nt = 0; nt < 4; nt++)
        acc[mt][nt] = (f32_4){0.0f, 0.0f, 0.0f, 0.0f};
#pragma unroll
    for (int ks = 0; ks < 4; ks++) {
      f16_8 Bk[4];
#pragma unroll
      for (int nt = 0; nt < 4; nt++)
        Bk[nt] = *(const f16_8*)(&Bs[0][(wn * 64 + nt * 16 + l16) * BSTRIDE + ks * 32 + quad * 8]);
#pragma unroll
      for (int mt = 0; mt < 2; mt++)
#pragma unroll
        for (int nt = 0; nt < 4; nt++)
          acc[mt][nt] = __builtin_amdgcn_mfma_f32_16x16x32_f16(Af[mt][ks], Bk[nt], acc[mt][nt], 0, 0, 0);
    }
#pragma unroll
    for (int mt = 0; mt < 2; mt++)
#pragma unroll
      for (int nt = 0; nt < 4; nt++)
#pragma unroll
        for (int r = 0; r < 4; r++) {
          int rowloc = wm * 32 + mt * 16 + quad * 4 + r;
          int slot = pblk + rowloc;
          int colL = (blockIdx.x & 1) * 128 + wn * 64 + nt * 16 + l16;
          if (slot < cnt && pb[rowloc] == batch)
            D[(size_t)slot * 256 + colL] = acc[mt][nt][r];
        }
    write_lds(1);
    __syncthreads();
    cur = 1;
  } else {
    load_src(queueTf + (size_t)nbase * CFM);
    write_lds(0);
    __syncthreads();
    cur = 0;
  }

#pragma unroll
  for (int ic = 0; ic < 8; ic++) {
    int n0 = nbase + ic * 128;
    if (ic + 1 < 8) load_src(queueTf + (size_t)(n0 + 128) * CFM);
    float2 qb[4];
#pragma unroll
    for (int nt = 0; nt < 4; nt++) qb[nt] = qeb[n0 + wn * 64 + nt * 16 + l16];

    f32_4 acc[2][4];
#pragma unroll
    for (int mt = 0; mt < 2; mt++)
#pragma unroll
      for (int nt = 0; nt < 4; nt++)
        acc[mt][nt] = (f32_4){0.0f, 0.0f, 0.0f, 0.0f};
#pragma unroll
    for (int ks = 0; ks < 4; ks++) {
      f16_8 Bk[4];
#pragma unroll
      for (int nt = 0; nt < 4; nt++)
        Bk[nt] = *(const f16_8*)(&Bs[cur][(wn * 64 + nt * 16 + l16) * BSTRIDE + ks * 32 + quad * 8]);
#pragma unroll
      for (int mt = 0; mt < 2; mt++)
#pragma unroll
        for (int nt = 0; nt < 4; nt++)
          acc[mt][nt] = __builtin_amdgcn_mfma_f32_16x16x32_f16(Af[mt][ks], Bk[nt], acc[mt][nt], 0, 0, 0);
    }
    if (ic + 1 < 8) write_lds(cur ^ 1);   // vmcnt wait lands here, after compute

#pragma unroll
    for (int nt = 0; nt < 4; nt++)
#pragma unroll
      for (int mt = 0; mt < 2; mt++)
#pragma unroll
        for (int r = 0; r < 4; r++)
          rowsum[mt][r] += exp2f(fmaf(acc[mt][nt][r], qb[nt].x, qb[nt].y));
    __syncthreads();
    cur ^= 1;
  }

#pragma unroll
  for (int mt = 0; mt < 2; mt++)
#pragma unroll
    for (int r = 0; r < 4; r++) {
      float vv = rowsum[mt][r];
      vv += __shfl_xor(vv, 1);
      vv += __shfl_xor(vv, 2);
      vv += __shfl_xor(vv, 4);
      vv += __shfl_xor(vv, 8);
      rowsum[mt][r] = vv;
    }
  if (l16 == 0) {
#pragma unroll
    for (int mt = 0; mt < 2; mt++)
#pragma unroll
      for (int r = 0; r < 4; r++)
        atomicAdd(&Srow[wm * 32 + mt * 16 + quad * 4 + r], rowsum[mt][r]);
  }
  __syncthreads();
  if (tid < 64) {
    int pr = pblk + tid;
    if (pr < cnt) atomicAdd(&S[list[pr]], Srow[tid]);
  }
}

// -------- negatives: wave-per-pixel, scalar via D + stats decomposition ----
__global__ __launch_bounds__(256) void k_negatives_lite(
    const float* __restrict__ D, const float* __restrict__ stats,
    const float* __restrict__ xr, float* __restrict__ S,
    const int* __restrict__ count, const int* __restrict__ list,
    uint32_t k1a, uint32_t k1b, uint32_t k2a, uint32_t k2b) {
  int tid = threadIdx.x;
  int wave = tid >> 6, lane = tid & 63;
  int cnt = *count;
  int slot = blockIdx.x * 4 + wave;
  if (slot >= cnt) return;
  int p = list[slot];
  int b = p >> 13;
  float esum = 0.0f;
  if (lane < NNEG) {
    uint32_t e = (uint32_t)(p * NNEG + lane);
    uint32_t h0, h1;
    threefry2x32(k1a, k1b, e, e + (uint32_t)NE, &h0, &h1);
    uint32_t off = ((h0 % 24u) * 16u + (h1 % 24u)) % 24u;
    float mag = (float)(1u + off);
    uint32_t ub;
    {
      uint32_t a, bm;
      if (e < EHALF_U) { threefry2x32(k2a, k2b, e, e + EHALF_U, &a, &bm); ub = a; }
      else             { threefry2x32(k2a, k2b, e - EHALF_U, e, &a, &bm); ub = bm; }
    }
    float u = __uint_as_float((ub >> 9) | 0x3F800000u) - 1.0f;
    float sg = (u > 0.5f) ? 1.0f : ((u < 0.5f) ? -1.0f : 0.0f);

    float v = xr[p] + mag * sg;
    float r = fmodf(v, 128.0f);
    if (r < 0.0f) r += 128.0f;
    float fx = r * (1.0f / 128.0f);
    float fy = fx * (1.0f / 64.0f);
    int x0i, x1i, y0i, y1i; float wx, wy;
    gs_coord(fx, 64.0f, 127.0f, &x0i, &x1i, &wx);
    gs_coord(fy, 32.0f, 63.0f, &y0i, &y1i, &wy);

    const float* Dp = D + (size_t)slot * 256;
    float d00 = Dp[x0i], d01 = Dp[x1i];
    float d10 = Dp[128 + x0i], d11 = Dp[128 + x1i];
    float u0 = 1.0f - wy, u1 = wy;
    float dv0 = u0 * d00 + u1 * d10;
    float dv1 = u0 * d01 + u1 * d11;
    float dot = (1.0f - wx) * dv0 + wx * dv1;

    const float* st0 = stats + (size_t)(b * 128 + x0i) * 8;
    const float* st1 = stats + (size_t)(b * 128 + x1i) * 8;
    float4 sa = *(const float4*)st0;
    float4 sb = *(const float4*)(st0 + 4);
    float4 sc = *(const float4*)st1;
    float a0 = u0 * u0, a1 = u0 * u1, a2 = u1 * u1;
    float nB0 = a0 * sa.x + 2.0f * a1 * sa.y + a2 * sa.z;
    float nB1 = a0 * sc.x + 2.0f * a1 * sc.y + a2 * sc.z;
    float cB  = a0 * sa.w + a1 * (sb.x + sb.y) + a2 * sb.z;
    float wx0 = 1.0f - wx;
    float nsq = wx0 * wx0 * nB0 + 2.0f * wx * wx0 * cB + wx * wx * nB1;
    float ln = dot / fmaxf(sqrtf(fmaxf(nsq, 0.0f)), 1e-12f);
    esum = __expf(ln * (1.0f / 0.07f) - MSHIFT);
  }
#pragma unroll
  for (int o = 32; o; o >>= 1) esum += __shfl_xor(esum, o, 64);
  if (lane == 0) atomicAdd(&S[p], esum);
}

__global__ __launch_bounds__(1024) void k_finalize(
    const float* __restrict__ S, const float* __restrict__ logit0,
    const float* __restrict__ maskArr, float* __restrict__ out) {
  int tid = threadIdx.x;
  const float cmask = logf(6061.0f);
  double acc = 0.0;
  for (int p = tid; p < NPIX; p += 1024) {
    float term = (maskArr[p] > 0.0f) ? (logf(S[p]) + MSHIFT - logit0[p]) : cmask;
    acc += (double)term;
  }
#pragma unroll
  for (int off = 32; off; off >>= 1) acc += __shfl_down(acc, off, 64);
  __shared__ double sd[16];
  if ((tid & 63) == 0) sd[tid >> 6] = acc;
  __syncthreads();
  if (tid == 0) {
    double tot = 0.0;
    for (int w = 0; w < 16; w++) tot += sd[w];
    out[0] = (float)(tot / (double)NPIX);
  }
}

extern "C" void kernel_launch(void* const* d_in, const int* in_sizes, int n_in,
                              void* d_out, int out_size, void* d_ws, size_t ws_size,
                              hipStream_t stream) {
  const float* ref   = (const float*)d_in[0];
  const float* tgt   = (const float*)d_in[1];
  const float* tl    = (const float*)d_in[2];
  const float* tr    = (const float*)d_in[3];
  const float* queue = (const float*)d_in[4];
  float* out = (float*)d_out;
  float* ws = (float*)d_ws;

  float2* qeb = (float2*)ws;                 // 6144 float2 -> 12288 floats
  float* S    = ws + 12288;                  // 16384
  float* lg0  = ws + 28672;                  // 16384
  float* mk   = ws + 45056;                  // 16384
  float* xr   = ws + 61440;                  // 16384 -> 77824
  int* count  = (int*)(ws + 77824);          // 1
  int* list   = (int*)(ws + 77840);          // 16384 -> 94224
  _Float16* QTf     = (_Float16*)(ws + 94464);    // NPIX*128 f16 (p-indexed)
  _Float16* queueTf = (_Float16*)(ws + 1143040);  // 6144*128 f16
  _Float16* tgtTf   = (_Float16*)(ws + 1536256);  // NPIX*128 f16
  _Float16* refTf   = (_Float16*)(ws + 2584832);  // NPIX*128 f16
  float* stats = ws + 3633408;                    // 2048
  float* D     = ws + 3635456;                    // NPIX*256 f32

  // JAX: k1, k2 = split(key(1234))
  uint32_t b0o0, b0o1, b1o0, b1o1;
  threefry2x32(0u, 1234u, 0u, 2u, &b0o0, &b0o1);
  threefry2x32(0u, 1234u, 1u, 3u, &b1o0, &b1o1);
  uint32_t k1a = b0o0, k1b = b1o0, k2a = b0o1, k2b = b1o1;

  k_A<<<dim3(4952), dim3(256), 0, stream>>>(ref, tgt, queue, tl, tr,
                                            refTf, tgtTf, queueTf, qeb, mk, xr);
  k_B<<<dim3(65 + 4096), dim3(256), 0, stream>>>(refTf, tgtTf, QTf, stats,
                                                 mk, xr, S, lg0, count, list);
  k_gemm<<<dim3(6, NPIX / 64), dim3(256), 0, stream>>>(QTf, queueTf, tgtTf, qeb,
                                                       S, D, count, list);
  k_negatives_lite<<<dim3(NPIX / 4), dim3(256), 0, stream>>>(D, stats, xr, S, count, list,
                                                             k1a, k1b, k2a, k2b);
  k_finalize<<<dim3(1), dim3(1024), 0, stream>>>(S, lg0, mk, out);
}